// Round 1
// 1050.056 us; speedup vs baseline: 1.0109x; 1.0109x over previous
//
#include <hip/hip_runtime.h>

// ---------------------------------------------------------------------------
// AdderNet 6-layer stack on MI355X (gfx950).
// out[n,o,p] = -sum_k |patch[p,k] - w[o,k]|   (VALU-bound; no MFMA possible)
// BN(batch stats)+ReLU6 of layer i folded into layer i+1's staging load.
//
// R3: 64pix x 128och tile, 4x8 micro (32 acc regs), split-K partial slices,
//     fused combine+stats kernel.
// R4: register-prefetch software pipeline. The old single-buffered
//     stage->__syncthreads->compute loop exposed the full global-load
//     latency every chunk (hipcc drains vmcnt(0) at __syncthreads), and at
//     2.8 blocks/CU there aren't enough waves to hide it (real VALU busy
//     ~36%; the 72% reported is the gfx94x 4cy-per-instr fallback formula).
//     Now: next chunk's global loads are issued into VGPRs right after the
//     LDS write phase, and raw s_barrier + manual lgkmcnt(0) (no vmcnt
//     drain!) lets them stay in flight under the 4096-cycle inner compute.
//     Also L4: Z 6->12 (fits the 23.6MB part buffer), grid 300->600.
// ---------------------------------------------------------------------------

template <bool IS3x3, bool BN>
__global__ __launch_bounds__(256, 4)
void adder_conv(const float* __restrict__ x, const float* __restrict__ wT,
                const float2* __restrict__ ab, float* __restrict__ part,
                int Cin, int H, int W, int Wo, int Cout,
                int stride, int pad, int cpz, int P, int PI, int Pp)
{
    constexpr int KC = 32;
    __shared__ float xs[KC][68];     // stride 68: conflict-light reads+writes
    __shared__ float ws[KC][128];
    __shared__ float2 abls[512];

    const int t  = threadIdx.x;
    const int tx = t & 15, ty = t >> 4;          // compute: 4 pix x 8 och
    const int ptile = blockIdx.x * 64, otile = blockIdx.y * 128;
    const int pp = t & 63, rg = t >> 6;          // xs staging: pixel, k-group
    const int oq = t & 31, kr = t >> 5;          // ws staging: och-quad, k-row

    if (BN) {
        for (int i = t; i < Cin; i += 256) abls[i] = ab[i];
        __syncthreads();
    }

    // staging pixel decode (fixed per thread)
    const int p_st = ptile + pp;
    const bool pv = p_st < P;
    int n_st = 0, q = 0;
    if (pv) { n_st = p_st / PI; q = p_st - n_st * PI; }
    const int oh = q / Wo, ow = q - oh * Wo;
    const int ih0 = oh * stride - pad, iw0 = ow * stride - pad;
    const int HWi = H * W;
    const float* xb = x + (size_t)n_st * Cin * HWi;

    float acc[4][8] = {};

    const int chunkBeg = blockIdx.z * cpz, chunkEnd = chunkBeg + cpz;

    // ---- prefetch registers (global -> VGPR, consumed next chunk)
    float  rx[8];
    float4 rw[4];

    auto issue_loads = [&](int ch) {
        const int k0 = ch * KC;
        int c0, ih, iw;
        if (IS3x3) {
            const int tap = k0 / Cin;            // uniform per chunk (Cin%32==0)
            c0 = k0 - tap * Cin;
            const int kh = tap / 3, kw = tap - kh * 3;
            ih = ih0 + kh; iw = iw0 + kw;
        } else { c0 = k0; ih = ih0; iw = iw0; }
        const bool valid = pv && (!IS3x3 || (ih >= 0 && ih < H && iw >= 0 && iw < W));
        const float* px = xb + (size_t)(c0 + rg) * HWi + (ih * W + iw);
#pragma unroll
        for (int j = 0; j < 8; ++j)
            rx[j] = valid ? px[(size_t)(4 * j) * HWi] : 0.f;
#pragma unroll
        for (int j = 0; j < 4; ++j)
            rw[j] = *(const float4*)&wT[(size_t)(k0 + kr + 8 * j) * Cout + otile + oq * 4];
    };

    auto write_lds = [&](int ch) {
        // recompute this chunk's validity/channel base (cheap scalar work)
        const int k0 = ch * KC;
        int c0; bool valid;
        if (IS3x3) {
            const int tap = k0 / Cin;
            c0 = k0 - tap * Cin;
            const int kh = tap / 3, kw = tap - kh * 3;
            const int ih = ih0 + kh, iw = iw0 + kw;
            valid = pv && ih >= 0 && ih < H && iw >= 0 && iw < W;
        } else { c0 = k0; valid = pv; }
#pragma unroll
        for (int j = 0; j < 8; ++j) {
            float v = rx[j];                     // rx==0 for invalid lanes
            if (BN) {
                const float2 s = abls[c0 + rg + 4 * j];
                v = fminf(fmaxf(fmaf(s.x, v, s.y), 0.f), 6.f);
                v = valid ? v : 0.f;             // padding stays literal 0
            }
            xs[rg + 4 * j][pp] = v;
        }
#pragma unroll
        for (int j = 0; j < 4; ++j)
            *(float4*)&ws[kr + 8 * j][oq * 4] = rw[j];
    };

    issue_loads(chunkBeg);

    for (int ch = chunkBeg; ch < chunkEnd; ++ch) {
        // [A] regs -> LDS (compiler inserts the vmcnt wait on first use of rx/rw)
        write_lds(ch);
        // [B] launch next chunk's global loads; they stay in flight across the
        //     barrier because we do NOT drain vmcnt here (raw s_barrier).
        if (ch + 1 < chunkEnd) issue_loads(ch + 1);
        // [C] only the LDS writes must be visible before the barrier
        asm volatile("s_waitcnt lgkmcnt(0)" ::: "memory");
        __builtin_amdgcn_s_barrier();
        asm volatile("" ::: "memory");

        // ---- inner: 3 ds_read_b128 + 64 VALU (sub + add-with-|mod|) per k
#pragma unroll 2
        for (int kk = 0; kk < KC; ++kk) {
            const float4 xv = *(const float4*)&xs[kk][tx * 4];
            const float4 wa = *(const float4*)&ws[kk][ty * 8];
            const float4 wb = *(const float4*)&ws[kk][ty * 8 + 4];
#define ACC1(I, XC)                                             \
            acc[I][0] += __builtin_fabsf(XC - wa.x);            \
            acc[I][1] += __builtin_fabsf(XC - wa.y);            \
            acc[I][2] += __builtin_fabsf(XC - wa.z);            \
            acc[I][3] += __builtin_fabsf(XC - wa.w);            \
            acc[I][4] += __builtin_fabsf(XC - wb.x);            \
            acc[I][5] += __builtin_fabsf(XC - wb.y);            \
            acc[I][6] += __builtin_fabsf(XC - wb.z);            \
            acc[I][7] += __builtin_fabsf(XC - wb.w);
            ACC1(0, xv.x) ACC1(1, xv.y) ACC1(2, xv.z) ACC1(3, xv.w)
#undef ACC1
        }
        // reads are all consumed (lgkmcnt drained by data deps); just fence order
        asm volatile("" ::: "memory");
        __builtin_amdgcn_s_barrier();
        asm volatile("" ::: "memory");
    }

    // ---- plain coalesced stores into this z-slice's partial buffer
    const int p0 = ptile + tx * 4;
    const bool full = (p0 + 3) < P;
#pragma unroll
    for (int jj = 0; jj < 8; ++jj) {
        const int o = otile + ty * 8 + jj;
        float* dst = part + ((size_t)blockIdx.z * Cout + o) * Pp + p0;
        if (full) {
            *(float4*)dst = make_float4(acc[0][jj], acc[1][jj], acc[2][jj], acc[3][jj]);
        } else {
#pragma unroll
            for (int i = 0; i < 4; ++i)
                if (p0 + i < P) dst[i] = acc[i][jj];
        }
    }
}

// fused: sum Z partial slices, negate -> final layout [n][c][PI], and
// accumulate per-channel sum/sumsq (double) for BN stats.
__global__ void combine_stats(const float* __restrict__ part, float* __restrict__ fin,
                              double* __restrict__ st, int C, int PI, int Z, int Pp)
{
    const int c = blockIdx.x, n = blockIdx.y, t = threadIdx.x;
    const int pbase = n * PI;
    double s = 0.0, s2 = 0.0;
    for (int qq = t; qq < PI; qq += 256) {
        float v = 0.f;
        for (int z = 0; z < Z; ++z)
            v += part[((size_t)z * C + c) * Pp + pbase + qq];
        v = -v;
        fin[((size_t)n * C + c) * PI + qq] = v;
        s += v; s2 += (double)v * v;
    }
    __shared__ double sh[256], sh2[256];
    sh[t] = s; sh2[t] = s2; __syncthreads();
    for (int off = 128; off > 0; off >>= 1) {
        if (t < off) { sh[t] += sh[t + off]; sh2[t] += sh2[t + off]; }
        __syncthreads();
    }
    if (t == 0) {
        unsafeAtomicAdd(&st[2 * c], sh[0]);
        unsafeAtomicAdd(&st[2 * c + 1], sh2[0]);
    }
}

// per-channel affine fold: a = g*rsqrt(var+eps), b = beta - mean*a
__global__ void ab_kernel(const double* __restrict__ st, const float* __restrict__ gamma,
                          const float* __restrict__ beta, float2* __restrict__ ab,
                          int C, double invCount)
{
    const int c = blockIdx.x * blockDim.x + threadIdx.x;
    if (c < C) {
        const double mean = st[2 * c] * invCount;
        const double var  = st[2 * c + 1] * invCount - mean * mean;
        const float a = gamma[c] * rsqrtf((float)var + 1e-5f);
        const float b = beta[c] - (float)mean * a;
        ab[c] = make_float2(a, b);
    }
}

// final BN+ReLU6 -> d_out
__global__ void apply_kernel(const float* __restrict__ y, const float2* __restrict__ ab,
                             float* __restrict__ out, int total, int C, int PI)
{
    const int i = blockIdx.x * 256 + threadIdx.x;
    if (i < total) {
        const int c = (i / PI) % C;
        const float2 s = ab[c];
        out[i] = fminf(fmaxf(fmaf(s.x, y[i], s.y), 0.f), 6.f);
    }
}

// merged weight transposes: w [Cout][Cin][tap] -> wT [tap*Cin + c][Cout]
struct TDesc { const float* w; float* wT; int Cout; int Cin; int Tap; int elems; };
struct TPack { TDesc d[6]; };

__global__ void transpose_all(TPack p)
{
    const TDesc d = p.d[blockIdx.y];
    const int i = blockIdx.x * 256 + threadIdx.x;
    if (i < d.elems) {
        const int k = i / d.Cout, o = i - k * d.Cout;
        const int tap = k / d.Cin, c = k - tap * d.Cin;
        d.wT[i] = d.w[((size_t)o * d.Cin + c) * d.Tap + tap];
    }
}

extern "C" void kernel_launch(void* const* d_in, const int* in_sizes, int n_in,
                              void* d_out, int out_size, void* d_ws, size_t ws_size,
                              hipStream_t stream)
{
    const float* x = (const float*)d_in[0];
    const float *w[6], *g[6], *bt[6];
    for (int i = 0; i < 6; ++i) {
        w[i]  = (const float*)d_in[1 + 3 * i];
        g[i]  = (const float*)d_in[2 + 3 * i];
        bt[i] = (const float*)d_in[3 + 3 * i];
    }

    char* ws = (char*)d_ws;
    float* bufA = (float*)ws;                                   // 23,658,496 B
    float* bufB = (float*)(ws + 23658496);                      // 11,829,248 B
    float* part = (float*)(ws + 23658496 + 11829248);           // 23,658,496 B
    size_t off = 23658496 + 11829248 + 23658496;
    const int wElems[6] = {256 * 512, 512 * 2304, 128 * 512,
                           256 * 1152, 128 * 256, 256 * 1152};
    float* wT[6];
    for (int i = 0; i < 6; ++i) { wT[i] = (float*)(ws + off); off += (size_t)wElems[i] * 4; }
    double* st = (double*)(ws + off); off += 3072 * 8;
    float2* ab = (float2*)(ws + off);
    const int stOff[6] = {0, 512, 1536, 1792, 2304, 2560};
    const int abOff[6] = {0, 256, 768, 896, 1152, 1280};

    const dim3 blk(256);

    // zero stats accumulators (ws is poisoned 0xAA before every launch)
    hipMemsetAsync(st, 0, 3072 * 8, stream);

    // merged weight transposes (tap-major k order)
    TPack tp;
    const int wCout[6] = {256, 512, 128, 256, 128, 256};
    const int wCin[6]  = {512, 256, 512, 128, 256, 128};
    const int wTap[6]  = {1, 9, 1, 9, 1, 9};
    for (int i = 0; i < 6; ++i)
        tp.d[i] = TDesc{w[i], wT[i], wCout[i], wCin[i], wTap[i], wElems[i]};
    transpose_all<<<dim3((1179648 + 255) / 256, 6), blk, 0, stream>>>(tp);

    // ---- L1: 1x1, 512->256, 38x38, P=23104, K=512, Z=1 (722 blocks)
    adder_conv<false, false><<<dim3(361, 2, 1), blk, 0, stream>>>(
        x, wT[0], nullptr, part, 512, 38, 38, 38, 256, 1, 0, 16, 23104, 1444, 23104);
    combine_stats<<<dim3(256, 16), blk, 0, stream>>>(part, bufA, st + stOff[0], 256, 1444, 1, 23104);
    ab_kernel<<<1, blk, 0, stream>>>(st + stOff[0], g[0], bt[0], ab + abOff[0], 256, 1.0 / 23104);

    // ---- L2: 3x3 s2 p1, 256->512, 38->19, P=5776, K=2304, Z=2 (728 blocks)
    adder_conv<true, true><<<dim3(91, 4, 2), blk, 0, stream>>>(
        bufA, wT[1], ab + abOff[0], part, 256, 38, 38, 19, 512, 2, 1, 36, 5776, 361, 5776);
    combine_stats<<<dim3(512, 16), blk, 0, stream>>>(part, bufB, st + stOff[1], 512, 361, 2, 5776);
    ab_kernel<<<2, blk, 0, stream>>>(st + stOff[1], g[1], bt[1], ab + abOff[1], 512, 1.0 / 5776);

    // ---- L3: 1x1, 512->128, 19x19, P=5776, K=512, Z=8 (728 blocks)
    adder_conv<false, true><<<dim3(91, 1, 8), blk, 0, stream>>>(
        bufB, wT[2], ab + abOff[1], part, 512, 19, 19, 19, 128, 1, 0, 2, 5776, 361, 5776);
    combine_stats<<<dim3(128, 16), blk, 0, stream>>>(part, bufA, st + stOff[2], 128, 361, 8, 5776);
    ab_kernel<<<1, blk, 0, stream>>>(st + stOff[2], g[2], bt[2], ab + abOff[2], 128, 1.0 / 5776);

    // ---- L4: 3x3 s2 p1, 128->256, 19->10, P=1600, K=1152, Z=12 (600 blocks)
    adder_conv<true, true><<<dim3(25, 2, 12), blk, 0, stream>>>(
        bufA, wT[3], ab + abOff[2], part, 128, 19, 19, 10, 256, 2, 1, 3, 1600, 100, 1600);
    combine_stats<<<dim3(256, 16), blk, 0, stream>>>(part, bufB, st + stOff[3], 256, 100, 12, 1600);
    ab_kernel<<<1, blk, 0, stream>>>(st + stOff[3], g[3], bt[3], ab + abOff[3], 256, 1.0 / 1600);

    // ---- L5: 1x1, 256->128, 10x10, P=1600, K=256, Z=8 (200 blocks)
    adder_conv<false, true><<<dim3(25, 1, 8), blk, 0, stream>>>(
        bufB, wT[4], ab + abOff[3], part, 256, 10, 10, 10, 128, 1, 0, 1, 1600, 100, 1600);
    combine_stats<<<dim3(128, 16), blk, 0, stream>>>(part, bufA, st + stOff[4], 128, 100, 8, 1600);
    ab_kernel<<<1, blk, 0, stream>>>(st + stOff[4], g[4], bt[4], ab + abOff[4], 128, 1.0 / 1600);

    // ---- L6: 3x3 s2 p0, 128->256, 10->4, P=256, K=1152, Z=18 (144 blocks)
    adder_conv<true, true><<<dim3(4, 2, 18), blk, 0, stream>>>(
        bufA, wT[5], ab + abOff[4], part, 128, 10, 10, 4, 256, 2, 0, 2, 256, 16, 256);
    combine_stats<<<dim3(256, 16), blk, 0, stream>>>(part, bufB, st + stOff[5], 256, 16, 18, 256);
    ab_kernel<<<1, blk, 0, stream>>>(st + stOff[5], g[5], bt[5], ab + abOff[5], 256, 1.0 / 256);

    // ---- final BN+ReLU6 -> out
    apply_kernel<<<(65536 + 255) / 256, blk, 0, stream>>>(bufB, ab + abOff[5], (float*)d_out,
                                                          65536, 256, 16);
}

// Round 2
// 994.990 us; speedup vs baseline: 1.0668x; 1.0553x over previous
//
#include <hip/hip_runtime.h>

// ---------------------------------------------------------------------------
// AdderNet 6-layer stack on MI355X (gfx950).
// out[n,o,p] = -sum_k |patch[p,k] - w[o,k]|   (VALU-bound; no MFMA possible)
// BN(batch stats)+ReLU6 of layer i folded into layer i+1's staging load.
//
// R3: 64pix x 128och tile, 4x8 micro (32 acc regs), split-K partial slices.
// R4: register-prefetch pipeline — FAILED: lambda-captured local ARRAYS
//     (rx[8]/rw[4]) were not promoted to registers; they spilled to scratch
//     (WRITE_SIZE 23MB -> 326MB, VGPR stayed 48). Latency theory untested.
// R5: same pipeline, spill-proof: prefetch lives in individually NAMED
//     scalar locals (xr0..xr7, wr0..wr3) — guaranteed SSA, immune to the
//     "memory" clobbers and to runtime indexing. No lambdas; macros inline
//     the issue/write phases. Raw s_barrier + lgkmcnt(0) only (vmcnt never
//     drained in-loop), so next chunk's 12 global loads stay in flight
//     under the 4096-cycle compute phase.
// ---------------------------------------------------------------------------

template <bool IS3x3, bool BN>
__global__ __launch_bounds__(256, 4)
void adder_conv(const float* __restrict__ x, const float* __restrict__ wT,
                const float2* __restrict__ ab, float* __restrict__ part,
                int Cin, int H, int W, int Wo, int Cout,
                int stride, int pad, int cpz, int P, int PI, int Pp)
{
    constexpr int KC = 32;
    __shared__ float xs[KC][68];     // stride 68: conflict-light reads+writes
    __shared__ float ws[KC][128];
    __shared__ float2 abls[512];

    const int t  = threadIdx.x;
    const int tx = t & 15, ty = t >> 4;          // compute: 4 pix x 8 och
    const int ptile = blockIdx.x * 64, otile = blockIdx.y * 128;
    const int pp = t & 63, rg = t >> 6;          // xs staging: pixel, k-group
    const int oq = t & 31, kr = t >> 5;          // ws staging: och-quad, k-row

    if (BN) {
        for (int i = t; i < Cin; i += 256) abls[i] = ab[i];
        __syncthreads();
    }

    // staging pixel decode (fixed per thread)
    const int p_st = ptile + pp;
    const bool pv = p_st < P;
    int n_st = 0, q = 0;
    if (pv) { n_st = p_st / PI; q = p_st - n_st * PI; }
    const int oh = q / Wo, ow = q - oh * Wo;
    const int ih0 = oh * stride - pad, iw0 = ow * stride - pad;
    const int HWi = H * W;
    const float* xb = x + (size_t)n_st * Cin * HWi;
    const float* wbase = wT + otile + oq * 4;

    float acc[4][8] = {};

    const int chunkBeg = blockIdx.z * cpz, chunkEnd = chunkBeg + cpz;

    // ---- prefetch state: NAMED scalars only (SSA; cannot spill via the
    //      asm "memory" clobbers, cannot be runtime-indexed to scratch)
    float  xr0, xr1, xr2, xr3, xr4, xr5, xr6, xr7;
    float4 wr0, wr1, wr2, wr3;
    int c0P = 0; bool vP = false;

#define ISSUE(CH) do {                                                        \
        const int k0_ = (CH) * KC;                                            \
        int c0_, ih_, iw_;                                                    \
        if (IS3x3) {                                                          \
            const int tap_ = k0_ / Cin;          /* uniform: Cin%32==0 */     \
            c0_ = k0_ - tap_ * Cin;                                           \
            const int kh_ = tap_ / 3, kw_ = tap_ - kh_ * 3;                   \
            ih_ = ih0 + kh_; iw_ = iw0 + kw_;                                 \
        } else { c0_ = k0_; ih_ = ih0; iw_ = iw0; }                           \
        vP = pv && (!IS3x3 || (ih_ >= 0 && ih_ < H && iw_ >= 0 && iw_ < W));  \
        c0P = c0_;                                                            \
        const float* px_ = xb + (size_t)(c0_ + rg) * HWi + (ih_ * W + iw_);   \
        xr0 = vP ? px_[0] : 0.f;                                              \
        xr1 = vP ? px_[(size_t) 4 * HWi] : 0.f;                               \
        xr2 = vP ? px_[(size_t) 8 * HWi] : 0.f;                               \
        xr3 = vP ? px_[(size_t)12 * HWi] : 0.f;                               \
        xr4 = vP ? px_[(size_t)16 * HWi] : 0.f;                               \
        xr5 = vP ? px_[(size_t)20 * HWi] : 0.f;                               \
        xr6 = vP ? px_[(size_t)24 * HWi] : 0.f;                               \
        xr7 = vP ? px_[(size_t)28 * HWi] : 0.f;                               \
        const float* pw_ = wbase + (size_t)(k0_ + kr) * Cout;                 \
        wr0 = *(const float4*)(pw_);                                          \
        wr1 = *(const float4*)(pw_ + (size_t) 8 * Cout);                      \
        wr2 = *(const float4*)(pw_ + (size_t)16 * Cout);                      \
        wr3 = *(const float4*)(pw_ + (size_t)24 * Cout);                      \
    } while (0)

#define BNAPPLY(V, J)                                                         \
        if (BN) {                                                             \
            const float2 s_ = abls[c0P + rg + 4 * (J)];                       \
            V = fminf(fmaxf(fmaf(s_.x, V, s_.y), 0.f), 6.f);                  \
            V = vP ? V : 0.f;        /* padding stays literal 0 */            \
        }

#define WRITE_LDS() do {                                                      \
        float v0_ = xr0, v1_ = xr1, v2_ = xr2, v3_ = xr3,                     \
              v4_ = xr4, v5_ = xr5, v6_ = xr6, v7_ = xr7;                     \
        BNAPPLY(v0_, 0) BNAPPLY(v1_, 1) BNAPPLY(v2_, 2) BNAPPLY(v3_, 3)       \
        BNAPPLY(v4_, 4) BNAPPLY(v5_, 5) BNAPPLY(v6_, 6) BNAPPLY(v7_, 7)       \
        xs[rg     ][pp] = v0_; xs[rg +  4][pp] = v1_;                         \
        xs[rg +  8][pp] = v2_; xs[rg + 12][pp] = v3_;                         \
        xs[rg + 16][pp] = v4_; xs[rg + 20][pp] = v5_;                         \
        xs[rg + 24][pp] = v6_; xs[rg + 28][pp] = v7_;                         \
        *(float4*)&ws[kr     ][oq * 4] = wr0;                                 \
        *(float4*)&ws[kr +  8][oq * 4] = wr1;                                 \
        *(float4*)&ws[kr + 16][oq * 4] = wr2;                                 \
        *(float4*)&ws[kr + 24][oq * 4] = wr3;                                 \
    } while (0)

    ISSUE(chunkBeg);

    for (int ch = chunkBeg; ch < chunkEnd; ++ch) {
        // [A] regs -> LDS (compiler inserts counted vmcnt waits on xr*/wr*)
        WRITE_LDS();
        // [B] launch next chunk's global loads; they stay in flight across
        //     the barrier because vmcnt is never drained in-loop.
        if (ch + 1 < chunkEnd) ISSUE(ch + 1);
        // [C] only the LDS writes must be visible before the barrier
        asm volatile("s_waitcnt lgkmcnt(0)" ::: "memory");
        __builtin_amdgcn_s_barrier();
        asm volatile("" ::: "memory");

        // ---- inner: 3 ds_read_b128 + 64 VALU (sub + add-with-|mod|) per k
#pragma unroll 2
        for (int kk = 0; kk < KC; ++kk) {
            const float4 xv = *(const float4*)&xs[kk][tx * 4];
            const float4 wa = *(const float4*)&ws[kk][ty * 8];
            const float4 wb = *(const float4*)&ws[kk][ty * 8 + 4];
#define ACC1(I, XC)                                             \
            acc[I][0] += __builtin_fabsf(XC - wa.x);            \
            acc[I][1] += __builtin_fabsf(XC - wa.y);            \
            acc[I][2] += __builtin_fabsf(XC - wa.z);            \
            acc[I][3] += __builtin_fabsf(XC - wa.w);            \
            acc[I][4] += __builtin_fabsf(XC - wb.x);            \
            acc[I][5] += __builtin_fabsf(XC - wb.y);            \
            acc[I][6] += __builtin_fabsf(XC - wb.z);            \
            acc[I][7] += __builtin_fabsf(XC - wb.w);
            ACC1(0, xv.x) ACC1(1, xv.y) ACC1(2, xv.z) ACC1(3, xv.w)
#undef ACC1
        }
        // reads all consumed by data deps; fence order around the barrier
        asm volatile("" ::: "memory");
        __builtin_amdgcn_s_barrier();
        asm volatile("" ::: "memory");
    }
#undef ISSUE
#undef BNAPPLY
#undef WRITE_LDS

    // ---- plain coalesced stores into this z-slice's partial buffer
    const int p0 = ptile + tx * 4;
    const bool full = (p0 + 3) < P;
#pragma unroll
    for (int jj = 0; jj < 8; ++jj) {
        const int o = otile + ty * 8 + jj;
        float* dst = part + ((size_t)blockIdx.z * Cout + o) * Pp + p0;
        if (full) {
            *(float4*)dst = make_float4(acc[0][jj], acc[1][jj], acc[2][jj], acc[3][jj]);
        } else {
#pragma unroll
            for (int i = 0; i < 4; ++i)
                if (p0 + i < P) dst[i] = acc[i][jj];
        }
    }
}

// fused: sum Z partial slices, negate -> final layout [n][c][PI], and
// accumulate per-channel sum/sumsq (double) for BN stats.
__global__ void combine_stats(const float* __restrict__ part, float* __restrict__ fin,
                              double* __restrict__ st, int C, int PI, int Z, int Pp)
{
    const int c = blockIdx.x, n = blockIdx.y, t = threadIdx.x;
    const int pbase = n * PI;
    double s = 0.0, s2 = 0.0;
    for (int qq = t; qq < PI; qq += 256) {
        float v = 0.f;
        for (int z = 0; z < Z; ++z)
            v += part[((size_t)z * C + c) * Pp + pbase + qq];
        v = -v;
        fin[((size_t)n * C + c) * PI + qq] = v;
        s += v; s2 += (double)v * v;
    }
    __shared__ double sh[256], sh2[256];
    sh[t] = s; sh2[t] = s2; __syncthreads();
    for (int off = 128; off > 0; off >>= 1) {
        if (t < off) { sh[t] += sh[t + off]; sh2[t] += sh2[t + off]; }
        __syncthreads();
    }
    if (t == 0) {
        unsafeAtomicAdd(&st[2 * c], sh[0]);
        unsafeAtomicAdd(&st[2 * c + 1], sh2[0]);
    }
}

// per-channel affine fold: a = g*rsqrt(var+eps), b = beta - mean*a
__global__ void ab_kernel(const double* __restrict__ st, const float* __restrict__ gamma,
                          const float* __restrict__ beta, float2* __restrict__ ab,
                          int C, double invCount)
{
    const int c = blockIdx.x * blockDim.x + threadIdx.x;
    if (c < C) {
        const double mean = st[2 * c] * invCount;
        const double var  = st[2 * c + 1] * invCount - mean * mean;
        const float a = gamma[c] * rsqrtf((float)var + 1e-5f);
        const float b = beta[c] - (float)mean * a;
        ab[c] = make_float2(a, b);
    }
}

// final BN+ReLU6 -> d_out
__global__ void apply_kernel(const float* __restrict__ y, const float2* __restrict__ ab,
                             float* __restrict__ out, int total, int C, int PI)
{
    const int i = blockIdx.x * 256 + threadIdx.x;
    if (i < total) {
        const int c = (i / PI) % C;
        const float2 s = ab[c];
        out[i] = fminf(fmaxf(fmaf(s.x, y[i], s.y), 0.f), 6.f);
    }
}

// merged weight transposes: w [Cout][Cin][tap] -> wT [tap*Cin + c][Cout]
struct TDesc { const float* w; float* wT; int Cout; int Cin; int Tap; int elems; };
struct TPack { TDesc d[6]; };

__global__ void transpose_all(TPack p)
{
    const TDesc d = p.d[blockIdx.y];
    const int i = blockIdx.x * 256 + threadIdx.x;
    if (i < d.elems) {
        const int k = i / d.Cout, o = i - k * d.Cout;
        const int tap = k / d.Cin, c = k - tap * d.Cin;
        d.wT[i] = d.w[((size_t)o * d.Cin + c) * d.Tap + tap];
    }
}

extern "C" void kernel_launch(void* const* d_in, const int* in_sizes, int n_in,
                              void* d_out, int out_size, void* d_ws, size_t ws_size,
                              hipStream_t stream)
{
    const float* x = (const float*)d_in[0];
    const float *w[6], *g[6], *bt[6];
    for (int i = 0; i < 6; ++i) {
        w[i]  = (const float*)d_in[1 + 3 * i];
        g[i]  = (const float*)d_in[2 + 3 * i];
        bt[i] = (const float*)d_in[3 + 3 * i];
    }

    char* ws = (char*)d_ws;
    float* bufA = (float*)ws;                                   // 23,658,496 B
    float* bufB = (float*)(ws + 23658496);                      // 11,829,248 B
    float* part = (float*)(ws + 23658496 + 11829248);           // 23,658,496 B
    size_t off = 23658496 + 11829248 + 23658496;
    const int wElems[6] = {256 * 512, 512 * 2304, 128 * 512,
                           256 * 1152, 128 * 256, 256 * 1152};
    float* wT[6];
    for (int i = 0; i < 6; ++i) { wT[i] = (float*)(ws + off); off += (size_t)wElems[i] * 4; }
    double* st = (double*)(ws + off); off += 3072 * 8;
    float2* ab = (float2*)(ws + off);
    const int stOff[6] = {0, 512, 1536, 1792, 2304, 2560};
    const int abOff[6] = {0, 256, 768, 896, 1152, 1280};

    const dim3 blk(256);

    // zero stats accumulators (ws is poisoned 0xAA before every launch)
    hipMemsetAsync(st, 0, 3072 * 8, stream);

    // merged weight transposes (tap-major k order)
    TPack tp;
    const int wCout[6] = {256, 512, 128, 256, 128, 256};
    const int wCin[6]  = {512, 256, 512, 128, 256, 128};
    const int wTap[6]  = {1, 9, 1, 9, 1, 9};
    for (int i = 0; i < 6; ++i)
        tp.d[i] = TDesc{w[i], wT[i], wCout[i], wCin[i], wTap[i], wElems[i]};
    transpose_all<<<dim3((1179648 + 255) / 256, 6), blk, 0, stream>>>(tp);

    // ---- L1: 1x1, 512->256, 38x38, P=23104, K=512, Z=1 (722 blocks)
    adder_conv<false, false><<<dim3(361, 2, 1), blk, 0, stream>>>(
        x, wT[0], nullptr, part, 512, 38, 38, 38, 256, 1, 0, 16, 23104, 1444, 23104);
    combine_stats<<<dim3(256, 16), blk, 0, stream>>>(part, bufA, st + stOff[0], 256, 1444, 1, 23104);
    ab_kernel<<<1, blk, 0, stream>>>(st + stOff[0], g[0], bt[0], ab + abOff[0], 256, 1.0 / 23104);

    // ---- L2: 3x3 s2 p1, 256->512, 38->19, P=5776, K=2304, Z=2 (728 blocks)
    adder_conv<true, true><<<dim3(91, 4, 2), blk, 0, stream>>>(
        bufA, wT[1], ab + abOff[0], part, 256, 38, 38, 19, 512, 2, 1, 36, 5776, 361, 5776);
    combine_stats<<<dim3(512, 16), blk, 0, stream>>>(part, bufB, st + stOff[1], 512, 361, 2, 5776);
    ab_kernel<<<2, blk, 0, stream>>>(st + stOff[1], g[1], bt[1], ab + abOff[1], 512, 1.0 / 5776);

    // ---- L3: 1x1, 512->128, 19x19, P=5776, K=512, Z=8 (728 blocks)
    adder_conv<false, true><<<dim3(91, 1, 8), blk, 0, stream>>>(
        bufB, wT[2], ab + abOff[1], part, 512, 19, 19, 19, 128, 1, 0, 2, 5776, 361, 5776);
    combine_stats<<<dim3(128, 16), blk, 0, stream>>>(part, bufA, st + stOff[2], 128, 361, 8, 5776);
    ab_kernel<<<1, blk, 0, stream>>>(st + stOff[2], g[2], bt[2], ab + abOff[2], 128, 1.0 / 5776);

    // ---- L4: 3x3 s2 p1, 128->256, 19->10, P=1600, K=1152, Z=12 (600 blocks)
    adder_conv<true, true><<<dim3(25, 2, 12), blk, 0, stream>>>(
        bufA, wT[3], ab + abOff[2], part, 128, 19, 19, 10, 256, 2, 1, 3, 1600, 100, 1600);
    combine_stats<<<dim3(256, 16), blk, 0, stream>>>(part, bufB, st + stOff[3], 256, 100, 12, 1600);
    ab_kernel<<<1, blk, 0, stream>>>(st + stOff[3], g[3], bt[3], ab + abOff[3], 256, 1.0 / 1600);

    // ---- L5: 1x1, 256->128, 10x10, P=1600, K=256, Z=8 (200 blocks)
    adder_conv<false, true><<<dim3(25, 1, 8), blk, 0, stream>>>(
        bufB, wT[4], ab + abOff[3], part, 256, 10, 10, 10, 128, 1, 0, 1, 1600, 100, 1600);
    combine_stats<<<dim3(128, 16), blk, 0, stream>>>(part, bufA, st + stOff[4], 128, 100, 8, 1600);
    ab_kernel<<<1, blk, 0, stream>>>(st + stOff[4], g[4], bt[4], ab + abOff[4], 128, 1.0 / 1600);

    // ---- L6: 3x3 s2 p0, 128->256, 10->4, P=256, K=1152, Z=18 (144 blocks)
    adder_conv<true, true><<<dim3(4, 2, 18), blk, 0, stream>>>(
        bufA, wT[5], ab + abOff[4], part, 128, 10, 10, 4, 256, 2, 0, 2, 256, 16, 256);
    combine_stats<<<dim3(256, 16), blk, 0, stream>>>(part, bufB, st + stOff[5], 256, 16, 18, 256);
    ab_kernel<<<1, blk, 0, stream>>>(st + stOff[5], g[5], bt[5], ab + abOff[5], 256, 1.0 / 256);

    // ---- final BN+ReLU6 -> out
    apply_kernel<<<(65536 + 255) / 256, blk, 0, stream>>>(bufB, ab + abOff[5], (float*)d_out,
                                                          65536, 256, 16);
}

// Round 3
// 965.427 us; speedup vs baseline: 1.0995x; 1.0306x over previous
//
#include <hip/hip_runtime.h>

// ---------------------------------------------------------------------------
// AdderNet 6-layer stack on MI355X (gfx950).
// out[n,o,p] = -sum_k |patch[p,k] - w[o,k]|   (VALU-bound; no MFMA possible)
// BN(batch stats)+ReLU6 of layer i folded into layer i+1's staging load.
//
// R3: 64pix x 128och tile, 4x8 micro, split-K partial slices.
// R4/R5: register-prefetch pipeline: defeated twice by the compiler (R4:
//     scratch spill, WRITE 326MB; R5: VGPR stayed 48 => loads parked in
//     AGPRs right after issue, latency NOT hidden). Lesson: hipcc will not
//     hold global-load results in VGPRs across a barrier at this pressure.
// R6: buy TLP instead of fighting for ILP. 64pix x 64och tile, 4x4 micro
//     (16 accs), grid doubles (L1 722->1444 blocks = 5.6/CU), LDS ~21KB,
//     launch_bounds(256,6). Occupancy 24% -> ~60-70%: stalls now hidden by
//     wave switching. Cost: +33% DS traffic/update, x re-read 4x (still
//     ~10x under HBM ceiling). Prefetch kept (16 floats now; may even fit).
// ---------------------------------------------------------------------------

template <bool IS3x3, bool BN>
__global__ __launch_bounds__(256, 6)
void adder_conv(const float* __restrict__ x, const float* __restrict__ wT,
                const float2* __restrict__ ab, float* __restrict__ part,
                int Cin, int H, int W, int Wo, int Cout,
                int stride, int pad, int cpz, int P, int PI, int Pp)
{
    constexpr int KC = 32;
    __shared__ float xs[KC][68];     // 64 pix, stride 68: conflict-light
    __shared__ float ws[KC][64];     // 64 och
    __shared__ float2 abls[512];

    const int t  = threadIdx.x;
    const int tx = t & 15, ty = t >> 4;          // compute: 4 pix x 4 och
    const int ptile = blockIdx.x * 64, otile = blockIdx.y * 64;
    const int pp = t & 63, rg = t >> 6;          // xs staging: pixel, k-group
    const int oq = t & 15, kr = t >> 4;          // ws staging: och-quad, k-row

    if (BN) {
        for (int i = t; i < Cin; i += 256) abls[i] = ab[i];
        __syncthreads();
    }

    // staging pixel decode (fixed per thread)
    const int p_st = ptile + pp;
    const bool pv = p_st < P;
    int n_st = 0, q = 0;
    if (pv) { n_st = p_st / PI; q = p_st - n_st * PI; }
    const int oh = q / Wo, ow = q - oh * Wo;
    const int ih0 = oh * stride - pad, iw0 = ow * stride - pad;
    const int HWi = H * W;
    const float* xb = x + (size_t)n_st * Cin * HWi;
    const float* wbase = wT + otile + oq * 4;

    float acc[4][4] = {};

    const int chunkBeg = blockIdx.z * cpz, chunkEnd = chunkBeg + cpz;

    // ---- prefetch state: NAMED scalars only
    float  xr0, xr1, xr2, xr3, xr4, xr5, xr6, xr7;
    float4 wr0, wr1;
    int c0P = 0; bool vP = false;

#define ISSUE(CH) do {                                                        \
        const int k0_ = (CH) * KC;                                            \
        int c0_, ih_, iw_;                                                    \
        if (IS3x3) {                                                          \
            const int tap_ = k0_ / Cin;          /* uniform: Cin%32==0 */     \
            c0_ = k0_ - tap_ * Cin;                                           \
            const int kh_ = tap_ / 3, kw_ = tap_ - kh_ * 3;                   \
            ih_ = ih0 + kh_; iw_ = iw0 + kw_;                                 \
        } else { c0_ = k0_; ih_ = ih0; iw_ = iw0; }                           \
        vP = pv && (!IS3x3 || (ih_ >= 0 && ih_ < H && iw_ >= 0 && iw_ < W));  \
        c0P = c0_;                                                            \
        const float* px_ = xb + (size_t)(c0_ + rg) * HWi + (ih_ * W + iw_);   \
        xr0 = vP ? px_[0] : 0.f;                                              \
        xr1 = vP ? px_[(size_t) 4 * HWi] : 0.f;                               \
        xr2 = vP ? px_[(size_t) 8 * HWi] : 0.f;                               \
        xr3 = vP ? px_[(size_t)12 * HWi] : 0.f;                               \
        xr4 = vP ? px_[(size_t)16 * HWi] : 0.f;                               \
        xr5 = vP ? px_[(size_t)20 * HWi] : 0.f;                               \
        xr6 = vP ? px_[(size_t)24 * HWi] : 0.f;                               \
        xr7 = vP ? px_[(size_t)28 * HWi] : 0.f;                               \
        const float* pw_ = wbase + (size_t)(k0_ + kr) * Cout;                 \
        wr0 = *(const float4*)(pw_);                                          \
        wr1 = *(const float4*)(pw_ + (size_t)16 * Cout);                      \
    } while (0)

#define BNAPPLY(V, J)                                                         \
        if (BN) {                                                             \
            const float2 s_ = abls[c0P + rg + 4 * (J)];                       \
            V = fminf(fmaxf(fmaf(s_.x, V, s_.y), 0.f), 6.f);                  \
            V = vP ? V : 0.f;        /* padding stays literal 0 */            \
        }

#define WRITE_LDS() do {                                                      \
        float v0_ = xr0, v1_ = xr1, v2_ = xr2, v3_ = xr3,                     \
              v4_ = xr4, v5_ = xr5, v6_ = xr6, v7_ = xr7;                     \
        BNAPPLY(v0_, 0) BNAPPLY(v1_, 1) BNAPPLY(v2_, 2) BNAPPLY(v3_, 3)       \
        BNAPPLY(v4_, 4) BNAPPLY(v5_, 5) BNAPPLY(v6_, 6) BNAPPLY(v7_, 7)       \
        xs[rg     ][pp] = v0_; xs[rg +  4][pp] = v1_;                         \
        xs[rg +  8][pp] = v2_; xs[rg + 12][pp] = v3_;                         \
        xs[rg + 16][pp] = v4_; xs[rg + 20][pp] = v5_;                         \
        xs[rg + 24][pp] = v6_; xs[rg + 28][pp] = v7_;                         \
        *(float4*)&ws[kr     ][oq * 4] = wr0;                                 \
        *(float4*)&ws[kr + 16][oq * 4] = wr1;                                 \
    } while (0)

    ISSUE(chunkBeg);

    for (int ch = chunkBeg; ch < chunkEnd; ++ch) {
        // [A] regs -> LDS
        WRITE_LDS();
        // [B] issue next chunk's global loads (vmcnt never drained in-loop)
        if (ch + 1 < chunkEnd) ISSUE(ch + 1);
        // [C] only the LDS writes must be visible before the barrier
        asm volatile("s_waitcnt lgkmcnt(0)" ::: "memory");
        __builtin_amdgcn_s_barrier();
        asm volatile("" ::: "memory");

        // ---- inner: 2 ds_read_b128 + 32 VALU per kk
#pragma unroll 4
        for (int kk = 0; kk < KC; ++kk) {
            const float4 xv = *(const float4*)&xs[kk][tx * 4];
            const float4 wa = *(const float4*)&ws[kk][ty * 4];
#define ACC1(I, XC)                                             \
            acc[I][0] += __builtin_fabsf(XC - wa.x);            \
            acc[I][1] += __builtin_fabsf(XC - wa.y);            \
            acc[I][2] += __builtin_fabsf(XC - wa.z);            \
            acc[I][3] += __builtin_fabsf(XC - wa.w);
            ACC1(0, xv.x) ACC1(1, xv.y) ACC1(2, xv.z) ACC1(3, xv.w)
#undef ACC1
        }
        asm volatile("" ::: "memory");
        __builtin_amdgcn_s_barrier();
        asm volatile("" ::: "memory");
    }
#undef ISSUE
#undef BNAPPLY
#undef WRITE_LDS

    // ---- plain coalesced stores into this z-slice's partial buffer
    const int p0 = ptile + tx * 4;
    const bool full = (p0 + 3) < P;
#pragma unroll
    for (int jj = 0; jj < 4; ++jj) {
        const int o = otile + ty * 4 + jj;
        float* dst = part + ((size_t)blockIdx.z * Cout + o) * Pp + p0;
        if (full) {
            *(float4*)dst = make_float4(acc[0][jj], acc[1][jj], acc[2][jj], acc[3][jj]);
        } else {
#pragma unroll
            for (int i = 0; i < 4; ++i)
                if (p0 + i < P) dst[i] = acc[i][jj];
        }
    }
}

// fused: sum Z partial slices, negate -> final layout [n][c][PI], and
// accumulate per-channel sum/sumsq (double) for BN stats.
__global__ void combine_stats(const float* __restrict__ part, float* __restrict__ fin,
                              double* __restrict__ st, int C, int PI, int Z, int Pp)
{
    const int c = blockIdx.x, n = blockIdx.y, t = threadIdx.x;
    const int pbase = n * PI;
    double s = 0.0, s2 = 0.0;
    for (int qq = t; qq < PI; qq += 256) {
        float v = 0.f;
        for (int z = 0; z < Z; ++z)
            v += part[((size_t)z * C + c) * Pp + pbase + qq];
        v = -v;
        fin[((size_t)n * C + c) * PI + qq] = v;
        s += v; s2 += (double)v * v;
    }
    __shared__ double sh[256], sh2[256];
    sh[t] = s; sh2[t] = s2; __syncthreads();
    for (int off = 128; off > 0; off >>= 1) {
        if (t < off) { sh[t] += sh[t + off]; sh2[t] += sh2[t + off]; }
        __syncthreads();
    }
    if (t == 0) {
        unsafeAtomicAdd(&st[2 * c], sh[0]);
        unsafeAtomicAdd(&st[2 * c + 1], sh2[0]);
    }
}

// per-channel affine fold: a = g*rsqrt(var+eps), b = beta - mean*a
__global__ void ab_kernel(const double* __restrict__ st, const float* __restrict__ gamma,
                          const float* __restrict__ beta, float2* __restrict__ ab,
                          int C, double invCount)
{
    const int c = blockIdx.x * blockDim.x + threadIdx.x;
    if (c < C) {
        const double mean = st[2 * c] * invCount;
        const double var  = st[2 * c + 1] * invCount - mean * mean;
        const float a = gamma[c] * rsqrtf((float)var + 1e-5f);
        const float b = beta[c] - (float)mean * a;
        ab[c] = make_float2(a, b);
    }
}

// final BN+ReLU6 -> d_out
__global__ void apply_kernel(const float* __restrict__ y, const float2* __restrict__ ab,
                             float* __restrict__ out, int total, int C, int PI)
{
    const int i = blockIdx.x * 256 + threadIdx.x;
    if (i < total) {
        const int c = (i / PI) % C;
        const float2 s = ab[c];
        out[i] = fminf(fmaxf(fmaf(s.x, y[i], s.y), 0.f), 6.f);
    }
}

// merged weight transposes: w [Cout][Cin][tap] -> wT [tap*Cin + c][Cout]
struct TDesc { const float* w; float* wT; int Cout; int Cin; int Tap; int elems; };
struct TPack { TDesc d[6]; };

__global__ void transpose_all(TPack p)
{
    const TDesc d = p.d[blockIdx.y];
    const int i = blockIdx.x * 256 + threadIdx.x;
    if (i < d.elems) {
        const int k = i / d.Cout, o = i - k * d.Cout;
        const int tap = k / d.Cin, c = k - tap * d.Cin;
        d.wT[i] = d.w[((size_t)o * d.Cin + c) * d.Tap + tap];
    }
}

extern "C" void kernel_launch(void* const* d_in, const int* in_sizes, int n_in,
                              void* d_out, int out_size, void* d_ws, size_t ws_size,
                              hipStream_t stream)
{
    const float* x = (const float*)d_in[0];
    const float *w[6], *g[6], *bt[6];
    for (int i = 0; i < 6; ++i) {
        w[i]  = (const float*)d_in[1 + 3 * i];
        g[i]  = (const float*)d_in[2 + 3 * i];
        bt[i] = (const float*)d_in[3 + 3 * i];
    }

    char* ws = (char*)d_ws;
    float* bufA = (float*)ws;                                   // 23,658,496 B
    float* bufB = (float*)(ws + 23658496);                      // 11,829,248 B
    float* part = (float*)(ws + 23658496 + 11829248);           // 23,658,496 B
    size_t off = 23658496 + 11829248 + 23658496;
    const int wElems[6] = {256 * 512, 512 * 2304, 128 * 512,
                           256 * 1152, 128 * 256, 256 * 1152};
    float* wT[6];
    for (int i = 0; i < 6; ++i) { wT[i] = (float*)(ws + off); off += (size_t)wElems[i] * 4; }
    double* st = (double*)(ws + off); off += 3072 * 8;
    float2* ab = (float2*)(ws + off);
    const int stOff[6] = {0, 512, 1536, 1792, 2304, 2560};
    const int abOff[6] = {0, 256, 768, 896, 1152, 1280};

    const dim3 blk(256);

    // zero stats accumulators (ws is poisoned 0xAA before every launch)
    hipMemsetAsync(st, 0, 3072 * 8, stream);

    // merged weight transposes (tap-major k order)
    TPack tp;
    const int wCout[6] = {256, 512, 128, 256, 128, 256};
    const int wCin[6]  = {512, 256, 512, 128, 256, 128};
    const int wTap[6]  = {1, 9, 1, 9, 1, 9};
    for (int i = 0; i < 6; ++i)
        tp.d[i] = TDesc{w[i], wT[i], wCout[i], wCin[i], wTap[i], wElems[i]};
    transpose_all<<<dim3((1179648 + 255) / 256, 6), blk, 0, stream>>>(tp);

    // ---- L1: 1x1, 512->256, 38x38, P=23104, K=512, Z=1 (1444 blocks)
    adder_conv<false, false><<<dim3(361, 4, 1), blk, 0, stream>>>(
        x, wT[0], nullptr, part, 512, 38, 38, 38, 256, 1, 0, 16, 23104, 1444, 23104);
    combine_stats<<<dim3(256, 16), blk, 0, stream>>>(part, bufA, st + stOff[0], 256, 1444, 1, 23104);
    ab_kernel<<<1, blk, 0, stream>>>(st + stOff[0], g[0], bt[0], ab + abOff[0], 256, 1.0 / 23104);

    // ---- L2: 3x3 s2 p1, 256->512, 38->19, P=5776, K=2304, Z=2 (1456 blocks)
    adder_conv<true, true><<<dim3(91, 8, 2), blk, 0, stream>>>(
        bufA, wT[1], ab + abOff[0], part, 256, 38, 38, 19, 512, 2, 1, 36, 5776, 361, 5776);
    combine_stats<<<dim3(512, 16), blk, 0, stream>>>(part, bufB, st + stOff[1], 512, 361, 2, 5776);
    ab_kernel<<<2, blk, 0, stream>>>(st + stOff[1], g[1], bt[1], ab + abOff[1], 512, 1.0 / 5776);

    // ---- L3: 1x1, 512->128, 19x19, P=5776, K=512, Z=8 (1456 blocks)
    adder_conv<false, true><<<dim3(91, 2, 8), blk, 0, stream>>>(
        bufB, wT[2], ab + abOff[1], part, 512, 19, 19, 19, 128, 1, 0, 2, 5776, 361, 5776);
    combine_stats<<<dim3(128, 16), blk, 0, stream>>>(part, bufA, st + stOff[2], 128, 361, 8, 5776);
    ab_kernel<<<1, blk, 0, stream>>>(st + stOff[2], g[2], bt[2], ab + abOff[2], 128, 1.0 / 5776);

    // ---- L4: 3x3 s2 p1, 128->256, 19->10, P=1600, K=1152, Z=12 (1200 blocks)
    adder_conv<true, true><<<dim3(25, 4, 12), blk, 0, stream>>>(
        bufA, wT[3], ab + abOff[2], part, 128, 19, 19, 10, 256, 2, 1, 3, 1600, 100, 1600);
    combine_stats<<<dim3(256, 16), blk, 0, stream>>>(part, bufB, st + stOff[3], 256, 100, 12, 1600);
    ab_kernel<<<1, blk, 0, stream>>>(st + stOff[3], g[3], bt[3], ab + abOff[3], 256, 1.0 / 1600);

    // ---- L5: 1x1, 256->128, 10x10, P=1600, K=256, Z=8 (400 blocks)
    adder_conv<false, true><<<dim3(25, 2, 8), blk, 0, stream>>>(
        bufB, wT[4], ab + abOff[3], part, 256, 10, 10, 10, 128, 1, 0, 1, 1600, 100, 1600);
    combine_stats<<<dim3(128, 16), blk, 0, stream>>>(part, bufA, st + stOff[4], 128, 100, 8, 1600);
    ab_kernel<<<1, blk, 0, stream>>>(st + stOff[4], g[4], bt[4], ab + abOff[4], 128, 1.0 / 1600);

    // ---- L6: 3x3 s2 p0, 128->256, 10->4, P=256, K=1152, Z=18 (288 blocks)
    adder_conv<true, true><<<dim3(4, 4, 18), blk, 0, stream>>>(
        bufA, wT[5], ab + abOff[4], part, 128, 10, 10, 4, 256, 2, 0, 2, 256, 16, 256);
    combine_stats<<<dim3(256, 16), blk, 0, stream>>>(part, bufB, st + stOff[5], 256, 16, 18, 256);
    ab_kernel<<<1, blk, 0, stream>>>(st + stOff[5], g[5], bt[5], ab + abOff[5], 256, 1.0 / 256);

    // ---- final BN+ReLU6 -> out
    apply_kernel<<<(65536 + 255) / 256, blk, 0, stream>>>(bufB, ab + abOff[5], (float*)d_out,
                                                          65536, 256, 16);
}

// Round 4
// 957.644 us; speedup vs baseline: 1.1084x; 1.0081x over previous
//
#include <hip/hip_runtime.h>

// ---------------------------------------------------------------------------
// AdderNet 6-layer stack on MI355X (gfx950).
// out[n,o,p] = -sum_k |patch[p,k] - w[o,k]|   (VALU-bound; no MFMA possible)
//
// R4/R5: VGPR-prefetch pipeline — collapsed by hipcc twice (scratch spill /
//        AGPR park). R6: occupancy 24->40%, dur unchanged => not wave-starved.
//        Top dispatch re-attributed to L2 (FETCH 799MB matches L2 staging
//        demand 839MB): VALU ~35%, DS-read ~33-49% there.
// R7: restructure:
//  - BN+ReLU6 applied per-layer by a separate elementwise kernel (fused
//    ab-computation); conv staging becomes a PURE copy.
//  - Staging via __builtin_amdgcn_global_load_lds into double-buffered LDS
//    [2][32][64] x2 operands (32KB), counted s_waitcnt vmcnt(S) + raw
//    s_barrier (m201 pattern). No result VGPRs => compiler cannot collapse
//    the pipeline; loads stay in flight across barriers.
//  - Invalid lanes (3x3 padding / tail pixels) read a memset zero page.
//  - XCD-chunked bijective block swizzle: each XCD owns a contiguous
//    pixel-tile range x all (och,z) groups => w cached per XCD, x read ~once.
// ---------------------------------------------------------------------------

typedef const __attribute__((address_space(1))) void* gvp_t;
typedef __attribute__((address_space(3))) void* svp_t;
#define GLDS(g, l, sz) \
    __builtin_amdgcn_global_load_lds((gvp_t)(const void*)(g), (svp_t)(void*)(l), sz, 0, 0)

// XW16: 1x1 layer whose PI % 4 == 0 (x staged with 16B/lane); else 4B/lane.
template <bool IS3x3, bool XW16>
__global__ __launch_bounds__(256, 4)
void adder_conv(const float* __restrict__ x, const float* __restrict__ wT,
                const float* __restrict__ zp, float* __restrict__ part,
                int Cin, int H, int W, int Wo, int Cout,
                int stride, int pad, int cpz, int P, int PI, int Pp,
                int G, int NY)
{
    constexpr int KC = 32;
    __shared__ float xs[2][KC][64];
    __shared__ float ws2[2][KC][64];

    const int t    = threadIdx.x;
    const int tx   = t & 15, ty = t >> 4;        // compute: 4 pix x 4 och
    const int wave = t >> 6, lane = t & 63;

    // ---- XCD-chunked bijective decode: hw f -> logical L (contiguous per XCD)
    const int f = blockIdx.x, ng = gridDim.x;
    const int qq8 = ng >> 3, rr8 = ng & 7;
    const int xcd = f & 7;
    const int L   = xcd * qq8 + (xcd < rr8 ? xcd : rr8) + (f >> 3);
    const int bxi = L / G, g = L - bxi * G;
    const int by  = g % NY, bz = g / NY;

    const int ptile = bxi * 64, otile = by * 64;
    const int HWi = H * W;

    const int chunkBeg = bz * cpz, chunkEnd = chunkBeg + cpz;
    const int k0i = chunkBeg * KC;

    // ---- weight staging source (per-lane; advances 32*Cout per chunk)
    const float* wsrc = wT + (size_t)(k0i + wave * 8 + (lane >> 4)) * Cout
                           + otile + (lane & 15) * 4;
    const size_t wstep = (size_t)KC * Cout;

    // ---- x staging state
    const float* xsrc = nullptr;      // XW16 / L3 path
    size_t xstep = 0, jstepL = 0;
    const float* xcur = nullptr;      // 3x3 path (per-tap)
    size_t cstep = 0, jstep3 = 0;
    const float* xb_pix = nullptr;
    int c0s = 0, kh = 0, kw = 0, ih0 = 0, iw0 = 0;
    bool pv = true;

    if (XW16) {
        // 4 consecutive pixels per lane, guaranteed same n (PI%4==0, exact tiles)
        const int p4 = ptile + (lane & 15) * 4;
        const int n4 = p4 / PI, q4 = p4 - n4 * PI;
        xsrc  = x + ((size_t)n4 * Cin + k0i + wave * 8 + (lane >> 4)) * HWi + q4;
        xstep = (size_t)KC * HWi;
    } else {
        const int p_st = ptile + lane;
        pv = p_st < P;
        int n_st = 0, q = 0;
        if (pv) { n_st = p_st / PI; q = p_st - n_st * PI; }
        const int oh = q / Wo, ow = q - oh * Wo;
        ih0 = oh * stride - pad; iw0 = ow * stride - pad;
        xb_pix = x + (size_t)n_st * Cin * HWi;
        if (!IS3x3) {
            // 1x1 width4 (L3): always in-bounds when pv
            xsrc   = pv ? (xb_pix + (size_t)k0i * HWi + q) : zp;
            jstepL = pv ? (size_t)HWi : 0;
            xstep  = pv ? (size_t)KC * HWi : 0;
        } else {
            const int tap = k0i / Cin;
            c0s = k0i - tap * Cin;
            kh = tap / 3; kw = tap - kh * 3;
            const int ih = ih0 + kh, iw = iw0 + kw;
            const bool vt = pv && ih >= 0 && ih < H && iw >= 0 && iw < W;
            xcur   = vt ? (xb_pix + (size_t)c0s * HWi + (ih * W + iw)) : zp;
            jstep3 = vt ? (size_t)HWi : 0;
            cstep  = vt ? (size_t)KC * HWi : 0;
        }
    }

#define STAGE(B) do {                                                         \
        if (XW16) {                                                           \
            GLDS(xsrc,                         &xs[B][wave * 8    ][0], 16);  \
            GLDS(xsrc + (size_t)4 * HWi,       &xs[B][wave * 8 + 4][0], 16);  \
        } else if (!IS3x3) {                                                  \
            _Pragma("unroll")                                                 \
            for (int j = 0; j < 8; ++j)                                       \
                GLDS(xsrc + (size_t)(wave * 8 + j) * jstepL,                  \
                     &xs[B][wave * 8 + j][0], 4);                             \
        } else {                                                              \
            _Pragma("unroll")                                                 \
            for (int j = 0; j < 8; ++j)                                       \
                GLDS(xcur + (size_t)(wave * 8 + j) * jstep3,                  \
                     &xs[B][wave * 8 + j][0], 4);                             \
        }                                                                     \
        GLDS(wsrc,                        &ws2[B][wave * 8    ][0], 16);      \
        GLDS(wsrc + (size_t)4 * Cout,     &ws2[B][wave * 8 + 4][0], 16);      \
    } while (0)

#define ADVANCE() do {                                                        \
        wsrc += wstep;                                                        \
        if (IS3x3) {                                                          \
            c0s += KC;                                                        \
            if (c0s == Cin) {                                                 \
                c0s = 0; ++kw; if (kw == 3) { kw = 0; ++kh; }                 \
                const int ih = ih0 + kh, iw = iw0 + kw;                       \
                const bool vt = pv && ih >= 0 && ih < H && iw >= 0 && iw < W; \
                xcur   = vt ? (xb_pix + (ih * W + iw)) : zp;                  \
                jstep3 = vt ? (size_t)HWi : 0;                                \
                cstep  = vt ? (size_t)KC * HWi : 0;                           \
            } else { xcur += cstep; }                                         \
        } else { xsrc += xstep; }                                             \
    } while (0)

    float acc[4][4] = {};

    STAGE(0);
    ADVANCE();

    for (int ch = chunkBeg; ch < chunkEnd; ++ch) {
        const int cur = (ch - chunkBeg) & 1;
        if (ch + 1 < chunkEnd) {
            STAGE(cur ^ 1);
            ADVANCE();
            // wait for buf[cur]'s loads only; the S just-issued stay in flight
            if (XW16) asm volatile("s_waitcnt vmcnt(4)" ::: "memory");
            else      asm volatile("s_waitcnt vmcnt(10)" ::: "memory");
        } else {
            asm volatile("s_waitcnt vmcnt(0)" ::: "memory");
        }
        __builtin_amdgcn_s_barrier();
        asm volatile("" ::: "memory");

        // ---- inner: 2 ds_read_b128 + 32 VALU per kk
        const float (*xsc)[64] = xs[cur];
        const float (*wsc)[64] = ws2[cur];
#pragma unroll 4
        for (int kk = 0; kk < KC; ++kk) {
            const float4 xv = *(const float4*)&xsc[kk][tx * 4];
            const float4 wa = *(const float4*)&wsc[kk][ty * 4];
#define ACC1(I, XC)                                             \
            acc[I][0] += __builtin_fabsf(XC - wa.x);            \
            acc[I][1] += __builtin_fabsf(XC - wa.y);            \
            acc[I][2] += __builtin_fabsf(XC - wa.z);            \
            acc[I][3] += __builtin_fabsf(XC - wa.w);
            ACC1(0, xv.x) ACC1(1, xv.y) ACC1(2, xv.z) ACC1(3, xv.w)
#undef ACC1
        }
        asm volatile("" ::: "memory");
        __builtin_amdgcn_s_barrier();   // protect buf[cur] before re-stage
        asm volatile("" ::: "memory");
    }
#undef STAGE
#undef ADVANCE

    // ---- plain coalesced stores into this z-slice's partial buffer
    const int p0 = ptile + tx * 4;
    const bool full = (p0 + 3) < P;
#pragma unroll
    for (int jj = 0; jj < 4; ++jj) {
        const int o = otile + ty * 4 + jj;
        float* dst = part + ((size_t)bz * Cout + o) * Pp + p0;
        if (full) {
            *(float4*)dst = make_float4(acc[0][jj], acc[1][jj], acc[2][jj], acc[3][jj]);
        } else {
#pragma unroll
            for (int i = 0; i < 4; ++i)
                if (p0 + i < P) dst[i] = acc[i][jj];
        }
    }
}

// fused: sum Z partial slices, negate -> final layout [n][c][PI], and
// accumulate per-channel sum/sumsq (double) for BN stats.
__global__ void combine_stats(const float* __restrict__ part, float* __restrict__ fin,
                              double* __restrict__ st, int C, int PI, int Z, int Pp)
{
    const int c = blockIdx.x, n = blockIdx.y, t = threadIdx.x;
    const int pbase = n * PI;
    double s = 0.0, s2 = 0.0;
    for (int qq = t; qq < PI; qq += 256) {
        float v = 0.f;
        for (int z = 0; z < Z; ++z)
            v += part[((size_t)z * C + c) * Pp + pbase + qq];
        v = -v;
        fin[((size_t)n * C + c) * PI + qq] = v;
        s += v; s2 += (double)v * v;
    }
    __shared__ double sh[256], sh2[256];
    sh[t] = s; sh2[t] = s2; __syncthreads();
    for (int off = 128; off > 0; off >>= 1) {
        if (t < off) { sh[t] += sh[t + off]; sh2[t] += sh2[t + off]; }
        __syncthreads();
    }
    if (t == 0) {
        unsafeAtomicAdd(&st[2 * c], sh[0]);
        unsafeAtomicAdd(&st[2 * c + 1], sh2[0]);
    }
}

// per-layer BN+ReLU6 with inline ab from stats (in-place capable)
__global__ void apply_kernel(const float* y, const double* __restrict__ st,
                             const float* __restrict__ gamma, const float* __restrict__ beta,
                             float* out, int total, int C, int PI, double invCount)
{
    const int i = blockIdx.x * 256 + threadIdx.x;
    if (i < total) {
        const int c = (i / PI) % C;
        const double mean = st[2 * c] * invCount;
        const double var  = st[2 * c + 1] * invCount - mean * mean;
        const float a = gamma[c] * rsqrtf((float)var + 1e-5f);
        const float b = beta[c] - (float)mean * a;
        out[i] = fminf(fmaxf(fmaf(a, y[i], b), 0.f), 6.f);
    }
}

// merged weight transposes: w [Cout][Cin][tap] -> wT [tap*Cin + c][Cout]
struct TDesc { const float* w; float* wT; int Cout; int Cin; int Tap; int elems; };
struct TPack { TDesc d[6]; };

__global__ void transpose_all(TPack p)
{
    const TDesc d = p.d[blockIdx.y];
    const int i = blockIdx.x * 256 + threadIdx.x;
    if (i < d.elems) {
        const int k = i / d.Cout, o = i - k * d.Cout;
        const int tap = k / d.Cin, c = k - tap * d.Cin;
        d.wT[i] = d.w[((size_t)o * d.Cin + c) * d.Tap + tap];
    }
}

extern "C" void kernel_launch(void* const* d_in, const int* in_sizes, int n_in,
                              void* d_out, int out_size, void* d_ws, size_t ws_size,
                              hipStream_t stream)
{
    const float* x = (const float*)d_in[0];
    const float *w[6], *g[6], *bt[6];
    for (int i = 0; i < 6; ++i) {
        w[i]  = (const float*)d_in[1 + 3 * i];
        g[i]  = (const float*)d_in[2 + 3 * i];
        bt[i] = (const float*)d_in[3 + 3 * i];
    }

    char* ws = (char*)d_ws;
    float* bufA = (float*)ws;                                   // 23,658,496 B
    float* bufB = (float*)(ws + 23658496);                      // 11,829,248 B
    float* part = (float*)(ws + 23658496 + 11829248);           // 23,658,496 B
    size_t off = 23658496 + 11829248 + 23658496;
    const int wElems[6] = {256 * 512, 512 * 2304, 128 * 512,
                           256 * 1152, 128 * 256, 256 * 1152};
    float* wT[6];
    for (int i = 0; i < 6; ++i) { wT[i] = (float*)(ws + off); off += (size_t)wElems[i] * 4; }
    double* st = (double*)(ws + off); off += 3072 * 8;
    float* zp = (float*)(ws + off); off += 256;                 // zero page
    const int stOff[6] = {0, 512, 1536, 1792, 2304, 2560};

    const dim3 blk(256);

    // zero stats accumulators + zero page (ws poisoned 0xAA before launch)
    hipMemsetAsync(st, 0, 3072 * 8 + 256, stream);

    // merged weight transposes (tap-major k order)
    TPack tp;
    const int wCout[6] = {256, 512, 128, 256, 128, 256};
    const int wCin[6]  = {512, 256, 512, 128, 256, 128};
    const int wTap[6]  = {1, 9, 1, 9, 1, 9};
    for (int i = 0; i < 6; ++i)
        tp.d[i] = TDesc{w[i], wT[i], wCout[i], wCin[i], wTap[i], wElems[i]};
    transpose_all<<<dim3((1179648 + 255) / 256, 6), blk, 0, stream>>>(tp);

    // ---- L1: 1x1, 512->256, 38x38, P=23104, K=512, Z=1, G=4 (1444 blocks)
    adder_conv<false, true><<<dim3(1444), blk, 0, stream>>>(
        x, wT[0], zp, part, 512, 38, 38, 38, 256, 1, 0, 16, 23104, 1444, 23104, 4, 4);
    combine_stats<<<dim3(256, 16), blk, 0, stream>>>(part, bufA, st + stOff[0], 256, 1444, 1, 23104);
    apply_kernel<<<(5914624 + 255) / 256, blk, 0, stream>>>(bufA, st + stOff[0], g[0], bt[0],
                                                            bufA, 5914624, 256, 1444, 1.0 / 23104);

    // ---- L2: 3x3 s2 p1, 256->512, 38->19, P=5776, K=2304, Z=2, G=16 (1456 blocks)
    adder_conv<true, false><<<dim3(1456), blk, 0, stream>>>(
        bufA, wT[1], zp, part, 256, 38, 38, 19, 512, 2, 1, 36, 5776, 361, 5776, 16, 8);
    combine_stats<<<dim3(512, 16), blk, 0, stream>>>(part, bufB, st + stOff[1], 512, 361, 2, 5776);
    apply_kernel<<<(2957312 + 255) / 256, blk, 0, stream>>>(bufB, st + stOff[1], g[1], bt[1],
                                                            bufB, 2957312, 512, 361, 1.0 / 5776);

    // ---- L3: 1x1, 512->128, 19x19, P=5776 (PI=361 %4!=0 -> width4), Z=8, G=16 (1456 blocks)
    adder_conv<false, false><<<dim3(1456), blk, 0, stream>>>(
        bufB, wT[2], zp, part, 512, 19, 19, 19, 128, 1, 0, 2, 5776, 361, 5776, 16, 2);
    combine_stats<<<dim3(128, 16), blk, 0, stream>>>(part, bufA, st + stOff[2], 128, 361, 8, 5776);
    apply_kernel<<<(739328 + 255) / 256, blk, 0, stream>>>(bufA, st + stOff[2], g[2], bt[2],
                                                           bufA, 739328, 128, 361, 1.0 / 5776);

    // ---- L4: 3x3 s2 p1, 128->256, 19->10, P=1600, K=1152, Z=12, G=48 (1200 blocks)
    adder_conv<true, false><<<dim3(1200), blk, 0, stream>>>(
        bufA, wT[3], zp, part, 128, 19, 19, 10, 256, 2, 1, 3, 1600, 100, 1600, 48, 4);
    combine_stats<<<dim3(256, 16), blk, 0, stream>>>(part, bufB, st + stOff[3], 256, 100, 12, 1600);
    apply_kernel<<<(409600 + 255) / 256, blk, 0, stream>>>(bufB, st + stOff[3], g[3], bt[3],
                                                           bufB, 409600, 256, 100, 1.0 / 1600);

    // ---- L5: 1x1, 256->128, 10x10, P=1600, PI=100 (%4==0 -> width16), Z=8, G=16 (400 blocks)
    adder_conv<false, true><<<dim3(400), blk, 0, stream>>>(
        bufB, wT[4], zp, part, 256, 10, 10, 10, 128, 1, 0, 1, 1600, 100, 1600, 16, 2);
    combine_stats<<<dim3(128, 16), blk, 0, stream>>>(part, bufA, st + stOff[4], 128, 100, 8, 1600);
    apply_kernel<<<(204800 + 255) / 256, blk, 0, stream>>>(bufA, st + stOff[4], g[4], bt[4],
                                                           bufA, 204800, 128, 100, 1.0 / 1600);

    // ---- L6: 3x3 s2 p0, 128->256, 10->4, P=256, K=1152, Z=18, G=72 (288 blocks)
    adder_conv<true, false><<<dim3(288), blk, 0, stream>>>(
        bufA, wT[5], zp, part, 128, 10, 10, 4, 256, 2, 0, 2, 256, 16, 256, 72, 4);
    combine_stats<<<dim3(256, 16), blk, 0, stream>>>(part, bufB, st + stOff[5], 256, 16, 18, 256);
    apply_kernel<<<(65536 + 255) / 256, blk, 0, stream>>>(bufB, st + stOff[5], g[5], bt[5],
                                                          (float*)d_out, 65536, 256, 16, 1.0 / 256);
}

// Round 5
// 671.649 us; speedup vs baseline: 1.5804x; 1.4258x over previous
//
#include <hip/hip_runtime.h>

// ---------------------------------------------------------------------------
// AdderNet 6-layer stack on MI355X (gfx950).
// out[n,o,p] = -sum_k |patch[p,k] - w[o,k]|
//
// R4-R7 established: L2-conv (the dominant dispatch) is invariant at
// ~530-570us across single/double-buffered staging, VGPR-prefetch, async
// global_load_lds, 118MB..856MB FETCH, 24..40% occupancy. Memory and
// occupancy are falsified as the bottleneck; the invariant is the inner
// VALU loop (2 fp32 instrs per update).
// R8: fixed-point + v_sad_u32 -> ONE instruction per update.
//   u = round(v * 2^17) + 2^20  (non-negative; offset cancels in |ux-uw|)
//   - w quantized once in transpose_all (wT is u32).
//   - x quantized in staging, fused after BN+ReLU6 (exact same fold as R6).
//   - inner: 2 ds_read_b128 + 16 v_sad_u32 per kk (was 32 VALU).
//   - integer accumulation exact; quant error ~1e-4 rms pre-BN.
//   - overflow: maxdiff ~8.3e5 * K=2304 = 1.9e9 < 2^32.
// Skeleton = R6 (VGPR-staged, named-scalar prefetch, 64x64 tile, 4x4 micro).
// ---------------------------------------------------------------------------

#define QSCALE 131072.0f            /* 2^17 */
#define QBIAS  1048576.5f           /* 2^20 + 0.5 (round-to-nearest via trunc) */
#define QINV   7.62939453125e-06    /* 2^-17, exact */

template <bool IS3x3, bool BN>
__global__ __launch_bounds__(256, 6)
void adder_conv(const float* __restrict__ x, const unsigned* __restrict__ wT,
                const float2* __restrict__ ab, unsigned* __restrict__ part,
                int Cin, int H, int W, int Wo, int Cout,
                int stride, int pad, int cpz, int P, int PI, int Pp)
{
    constexpr int KC = 32;
    __shared__ unsigned xs[KC][68];  // 64 pix, stride 68: conflict-light
    __shared__ unsigned ws[KC][64];  // 64 och
    __shared__ float2 abls[512];

    const int t  = threadIdx.x;
    const int tx = t & 15, ty = t >> 4;          // compute: 4 pix x 4 och
    const int ptile = blockIdx.x * 64, otile = blockIdx.y * 64;
    const int pp = t & 63, rg = t >> 6;          // xs staging: pixel, k-group
    const int oq = t & 15, kr = t >> 4;          // ws staging: och-quad, k-row

    if (BN) {
        for (int i = t; i < Cin; i += 256) abls[i] = ab[i];
        __syncthreads();
    }

    // staging pixel decode (fixed per thread)
    const int p_st = ptile + pp;
    const bool pv = p_st < P;
    int n_st = 0, q = 0;
    if (pv) { n_st = p_st / PI; q = p_st - n_st * PI; }
    const int oh = q / Wo, ow = q - oh * Wo;
    const int ih0 = oh * stride - pad, iw0 = ow * stride - pad;
    const int HWi = H * W;
    const float* xb = x + (size_t)n_st * Cin * HWi;
    const unsigned* wbase = wT + otile + oq * 4;

    unsigned acc[4][4] = {};

    const int chunkBeg = blockIdx.z * cpz, chunkEnd = chunkBeg + cpz;

    // ---- prefetch state: NAMED scalars only
    float xr0, xr1, xr2, xr3, xr4, xr5, xr6, xr7;
    uint4 wr0, wr1;
    int c0P = 0; bool vP = false;

#define ISSUE(CH) do {                                                        \
        const int k0_ = (CH) * KC;                                            \
        int c0_, ih_, iw_;                                                    \
        if (IS3x3) {                                                          \
            const int tap_ = k0_ / Cin;          /* uniform: Cin%32==0 */     \
            c0_ = k0_ - tap_ * Cin;                                           \
            const int kh_ = tap_ / 3, kw_ = tap_ - kh_ * 3;                   \
            ih_ = ih0 + kh_; iw_ = iw0 + kw_;                                 \
        } else { c0_ = k0_; ih_ = ih0; iw_ = iw0; }                           \
        vP = pv && (!IS3x3 || (ih_ >= 0 && ih_ < H && iw_ >= 0 && iw_ < W));  \
        c0P = c0_;                                                            \
        const float* px_ = xb + (size_t)(c0_ + rg) * HWi + (ih_ * W + iw_);   \
        xr0 = vP ? px_[0] : 0.f;                                              \
        xr1 = vP ? px_[(size_t) 4 * HWi] : 0.f;                               \
        xr2 = vP ? px_[(size_t) 8 * HWi] : 0.f;                               \
        xr3 = vP ? px_[(size_t)12 * HWi] : 0.f;                               \
        xr4 = vP ? px_[(size_t)16 * HWi] : 0.f;                               \
        xr5 = vP ? px_[(size_t)20 * HWi] : 0.f;                               \
        xr6 = vP ? px_[(size_t)24 * HWi] : 0.f;                               \
        xr7 = vP ? px_[(size_t)28 * HWi] : 0.f;                               \
        const unsigned* pw_ = wbase + (size_t)(k0_ + kr) * Cout;              \
        wr0 = *(const uint4*)(pw_);                                           \
        wr1 = *(const uint4*)(pw_ + (size_t)16 * Cout);                       \
    } while (0)

    // BN (optional) then quantize: u = trunc(v*2^17 + 2^20 + 0.5)
#define BNQ(V, J, DST)                                                        \
        {                                                                     \
            float vv_ = V;                                                    \
            if (BN) {                                                         \
                const float2 s_ = abls[c0P + rg + 4 * (J)];                   \
                vv_ = fminf(fmaxf(fmaf(s_.x, vv_, s_.y), 0.f), 6.f);          \
                vv_ = vP ? vv_ : 0.f;      /* padding stays literal 0 */      \
            }                                                                 \
            DST = (unsigned)fmaf(vv_, QSCALE, QBIAS);                         \
        }

#define WRITE_LDS() do {                                                      \
        unsigned q0_, q1_, q2_, q3_, q4_, q5_, q6_, q7_;                      \
        BNQ(xr0, 0, q0_) BNQ(xr1, 1, q1_) BNQ(xr2, 2, q2_) BNQ(xr3, 3, q3_)   \
        BNQ(xr4, 4, q4_) BNQ(xr5, 5, q5_) BNQ(xr6, 6, q6_) BNQ(xr7, 7, q7_)   \
        xs[rg     ][pp] = q0_; xs[rg +  4][pp] = q1_;                         \
        xs[rg +  8][pp] = q2_; xs[rg + 12][pp] = q3_;                         \
        xs[rg + 16][pp] = q4_; xs[rg + 20][pp] = q5_;                         \
        xs[rg + 24][pp] = q6_; xs[rg + 28][pp] = q7_;                         \
        *(uint4*)&ws[kr     ][oq * 4] = wr0;                                  \
        *(uint4*)&ws[kr + 16][oq * 4] = wr1;                                  \
    } while (0)

    ISSUE(chunkBeg);

    for (int ch = chunkBeg; ch < chunkEnd; ++ch) {
        // [A] regs -> LDS (BN + quantize fused)
        WRITE_LDS();
        // [B] issue next chunk's global loads (vmcnt never drained in-loop)
        if (ch + 1 < chunkEnd) ISSUE(ch + 1);
        // [C] only the LDS writes must be visible before the barrier
        asm volatile("s_waitcnt lgkmcnt(0)" ::: "memory");
        __builtin_amdgcn_s_barrier();
        asm volatile("" ::: "memory");

        // ---- inner: 2 ds_read_b128 + 16 v_sad_u32 per kk
#pragma unroll 4
        for (int kk = 0; kk < KC; ++kk) {
            const uint4 xv = *(const uint4*)&xs[kk][tx * 4];
            const uint4 wa = *(const uint4*)&ws[kk][ty * 4];
#define SAD1(I, J, XC, WC) \
            asm("v_sad_u32 %0, %1, %2, %0" : "+v"(acc[I][J]) : "v"(XC), "v"(WC));
#define SADROW(I, XC) \
            SAD1(I, 0, XC, wa.x) SAD1(I, 1, XC, wa.y) \
            SAD1(I, 2, XC, wa.z) SAD1(I, 3, XC, wa.w)
            SADROW(0, xv.x) SADROW(1, xv.y) SADROW(2, xv.z) SADROW(3, xv.w)
#undef SADROW
#undef SAD1
        }
        asm volatile("" ::: "memory");
        __builtin_amdgcn_s_barrier();
        asm volatile("" ::: "memory");
    }
#undef ISSUE
#undef BNQ
#undef WRITE_LDS

    // ---- plain coalesced stores into this z-slice's partial buffer
    const int p0 = ptile + tx * 4;
    const bool full = (p0 + 3) < P;
#pragma unroll
    for (int jj = 0; jj < 4; ++jj) {
        const int o = otile + ty * 4 + jj;
        unsigned* dst = part + ((size_t)blockIdx.z * Cout + o) * Pp + p0;
        if (full) {
            *(uint4*)dst = make_uint4(acc[0][jj], acc[1][jj], acc[2][jj], acc[3][jj]);
        } else {
#pragma unroll
            for (int i = 0; i < 4; ++i)
                if (p0 + i < P) dst[i] = acc[i][jj];
        }
    }
}

// fused: sum Z u32 partial slices, rescale + negate -> float [n][c][PI], and
// accumulate per-channel sum/sumsq (double) for BN stats.
__global__ void combine_stats(const unsigned* __restrict__ part, float* __restrict__ fin,
                              double* __restrict__ st, int C, int PI, int Z, int Pp)
{
    const int c = blockIdx.x, n = blockIdx.y, t = threadIdx.x;
    const int pbase = n * PI;
    double s = 0.0, s2 = 0.0;
    for (int qq = t; qq < PI; qq += 256) {
        unsigned long long u = 0;
        for (int z = 0; z < Z; ++z)
            u += part[((size_t)z * C + c) * Pp + pbase + qq];
        const float v = -(float)((double)u * QINV);
        fin[((size_t)n * C + c) * PI + qq] = v;
        s += v; s2 += (double)v * v;
    }
    __shared__ double sh[256], sh2[256];
    sh[t] = s; sh2[t] = s2; __syncthreads();
    for (int off = 128; off > 0; off >>= 1) {
        if (t < off) { sh[t] += sh[t + off]; sh2[t] += sh2[t + off]; }
        __syncthreads();
    }
    if (t == 0) {
        unsafeAtomicAdd(&st[2 * c], sh[0]);
        unsafeAtomicAdd(&st[2 * c + 1], sh2[0]);
    }
}

// per-channel affine fold: a = g*rsqrt(var+eps), b = beta - mean*a
__global__ void ab_kernel(const double* __restrict__ st, const float* __restrict__ gamma,
                          const float* __restrict__ beta, float2* __restrict__ ab,
                          int C, double invCount)
{
    const int c = blockIdx.x * blockDim.x + threadIdx.x;
    if (c < C) {
        const double mean = st[2 * c] * invCount;
        const double var  = st[2 * c + 1] * invCount - mean * mean;
        const float a = gamma[c] * rsqrtf((float)var + 1e-5f);
        const float b = beta[c] - (float)mean * a;
        ab[c] = make_float2(a, b);
    }
}

// final BN+ReLU6 -> d_out
__global__ void apply_kernel(const float* __restrict__ y, const float2* __restrict__ ab,
                             float* __restrict__ out, int total, int C, int PI)
{
    const int i = blockIdx.x * 256 + threadIdx.x;
    if (i < total) {
        const int c = (i / PI) % C;
        const float2 s = ab[c];
        out[i] = fminf(fmaxf(fmaf(s.x, y[i], s.y), 0.f), 6.f);
    }
}

// merged weight transposes + fixed-point quantize:
// w [Cout][Cin][tap] -> wT [tap*Cin + c][Cout], u32 = round(w*2^17) + 2^20
struct TDesc { const float* w; unsigned* wT; int Cout; int Cin; int Tap; int elems; };
struct TPack { TDesc d[6]; };

__global__ void transpose_all(TPack p)
{
    const TDesc d = p.d[blockIdx.y];
    const int i = blockIdx.x * 256 + threadIdx.x;
    if (i < d.elems) {
        const int k = i / d.Cout, o = i - k * d.Cout;
        const int tap = k / d.Cin, c = k - tap * d.Cin;
        const float v = d.w[((size_t)o * d.Cin + c) * d.Tap + tap];
        d.wT[i] = (unsigned)fmaf(v, QSCALE, QBIAS);
    }
}

extern "C" void kernel_launch(void* const* d_in, const int* in_sizes, int n_in,
                              void* d_out, int out_size, void* d_ws, size_t ws_size,
                              hipStream_t stream)
{
    const float* x = (const float*)d_in[0];
    const float *w[6], *g[6], *bt[6];
    for (int i = 0; i < 6; ++i) {
        w[i]  = (const float*)d_in[1 + 3 * i];
        g[i]  = (const float*)d_in[2 + 3 * i];
        bt[i] = (const float*)d_in[3 + 3 * i];
    }

    char* ws = (char*)d_ws;
    float* bufA = (float*)ws;                                   // 23,658,496 B
    float* bufB = (float*)(ws + 23658496);                      // 11,829,248 B
    unsigned* part = (unsigned*)(ws + 23658496 + 11829248);     // 23,658,496 B
    size_t off = 23658496 + 11829248 + 23658496;
    const int wElems[6] = {256 * 512, 512 * 2304, 128 * 512,
                           256 * 1152, 128 * 256, 256 * 1152};
    unsigned* wT[6];
    for (int i = 0; i < 6; ++i) { wT[i] = (unsigned*)(ws + off); off += (size_t)wElems[i] * 4; }
    double* st = (double*)(ws + off); off += 3072 * 8;
    float2* ab = (float2*)(ws + off);
    const int stOff[6] = {0, 512, 1536, 1792, 2304, 2560};
    const int abOff[6] = {0, 256, 768, 896, 1152, 1280};

    const dim3 blk(256);

    // zero stats accumulators (ws is poisoned 0xAA before every launch)
    hipMemsetAsync(st, 0, 3072 * 8, stream);

    // merged weight transposes (tap-major k order) + quantize
    TPack tp;
    const int wCout[6] = {256, 512, 128, 256, 128, 256};
    const int wCin[6]  = {512, 256, 512, 128, 256, 128};
    const int wTap[6]  = {1, 9, 1, 9, 1, 9};
    for (int i = 0; i < 6; ++i)
        tp.d[i] = TDesc{w[i], wT[i], wCout[i], wCin[i], wTap[i], wElems[i]};
    transpose_all<<<dim3((1179648 + 255) / 256, 6), blk, 0, stream>>>(tp);

    // ---- L1: 1x1, 512->256, 38x38, P=23104, K=512, Z=1 (1444 blocks)
    adder_conv<false, false><<<dim3(361, 4, 1), blk, 0, stream>>>(
        x, wT[0], nullptr, part, 512, 38, 38, 38, 256, 1, 0, 16, 23104, 1444, 23104);
    combine_stats<<<dim3(256, 16), blk, 0, stream>>>(part, bufA, st + stOff[0], 256, 1444, 1, 23104);
    ab_kernel<<<1, blk, 0, stream>>>(st + stOff[0], g[0], bt[0], ab + abOff[0], 256, 1.0 / 23104);

    // ---- L2: 3x3 s2 p1, 256->512, 38->19, P=5776, K=2304, Z=2 (1456 blocks)
    adder_conv<true, true><<<dim3(91, 8, 2), blk, 0, stream>>>(
        bufA, wT[1], ab + abOff[0], part, 256, 38, 38, 19, 512, 2, 1, 36, 5776, 361, 5776);
    combine_stats<<<dim3(512, 16), blk, 0, stream>>>(part, bufB, st + stOff[1], 512, 361, 2, 5776);
    ab_kernel<<<2, blk, 0, stream>>>(st + stOff[1], g[1], bt[1], ab + abOff[1], 512, 1.0 / 5776);

    // ---- L3: 1x1, 512->128, 19x19, P=5776, K=512, Z=8 (1456 blocks)
    adder_conv<false, true><<<dim3(91, 2, 8), blk, 0, stream>>>(
        bufB, wT[2], ab + abOff[1], part, 512, 19, 19, 19, 128, 1, 0, 2, 5776, 361, 5776);
    combine_stats<<<dim3(128, 16), blk, 0, stream>>>(part, bufA, st + stOff[2], 128, 361, 8, 5776);
    ab_kernel<<<1, blk, 0, stream>>>(st + stOff[2], g[2], bt[2], ab + abOff[2], 128, 1.0 / 5776);

    // ---- L4: 3x3 s2 p1, 128->256, 19->10, P=1600, K=1152, Z=12 (1200 blocks)
    adder_conv<true, true><<<dim3(25, 4, 12), blk, 0, stream>>>(
        bufA, wT[3], ab + abOff[2], part, 128, 19, 19, 10, 256, 2, 1, 3, 1600, 100, 1600);
    combine_stats<<<dim3(256, 16), blk, 0, stream>>>(part, bufB, st + stOff[3], 256, 100, 12, 1600);
    ab_kernel<<<1, blk, 0, stream>>>(st + stOff[3], g[3], bt[3], ab + abOff[3], 256, 1.0 / 1600);

    // ---- L5: 1x1, 256->128, 10x10, P=1600, K=256, Z=8 (400 blocks)
    adder_conv<false, true><<<dim3(25, 2, 8), blk, 0, stream>>>(
        bufB, wT[4], ab + abOff[3], part, 256, 10, 10, 10, 128, 1, 0, 1, 1600, 100, 1600);
    combine_stats<<<dim3(128, 16), blk, 0, stream>>>(part, bufA, st + stOff[4], 128, 100, 8, 1600);
    ab_kernel<<<1, blk, 0, stream>>>(st + stOff[4], g[4], bt[4], ab + abOff[4], 128, 1.0 / 1600);

    // ---- L6: 3x3 s2 p0, 128->256, 10->4, P=256, K=1152, Z=18 (288 blocks)
    adder_conv<true, true><<<dim3(4, 4, 18), blk, 0, stream>>>(
        bufA, wT[5], ab + abOff[4], part, 128, 10, 10, 4, 256, 2, 0, 2, 256, 16, 256);
    combine_stats<<<dim3(256, 16), blk, 0, stream>>>(part, bufB, st + stOff[5], 256, 16, 18, 256);
    ab_kernel<<<1, blk, 0, stream>>>(st + stOff[5], g[5], bt[5], ab + abOff[5], 256, 1.0 / 256);

    // ---- final BN+ReLU6 -> out
    apply_kernel<<<(65536 + 255) / 256, blk, 0, stream>>>(bufB, ab + abOff[5], (float*)d_out,
                                                          65536, 256, 16);
}

// Round 8
// 668.751 us; speedup vs baseline: 1.5873x; 1.0043x over previous
//
#include <hip/hip_runtime.h>

// ---------------------------------------------------------------------------
// AdderNet 6-layer stack on MI355X (gfx950).
// out[n,o,p] = -sum_k |patch[p,k] - w[o,k]|
//
// R8 (v_sad_u32 fixed-point, 64x64 tile, 4x4 micro): PASSED, 672us total,
//     L2-conv 314us = LDS-read-bound (2 B/update, DS floor ~263us).
// R9 (128x128 + global_load_lds dbuf + applyq split): FAILED absmax 3.3 —
//     too many variables at once. Lesson re-learned: one variable per round.
// R10: R8 base + ONE change: 64x128 tile, 4x8 micro (geometry proven in the
//     round-2 float kernel). Per kk: 1 uint4 x + 2 uint4 w per thread for
//     32 sad-updates = 1.5 B/update (-25% DS traffic). Everything else
//     (staging, BNQ quantization, z-splits, combine/ab/apply) = R8 verbatim.
// R11: resubmit of R10 unchanged (previous round died to a container infra
//     failure before compile/run; no measurement happened).
// ---------------------------------------------------------------------------

#define QSCALE 131072.0f            /* 2^17 */
#define QBIAS  1048576.5f           /* 2^20 + 0.5 (round via trunc) */
#define QINV   7.62939453125e-06    /* 2^-17 */

template <bool IS3x3, bool BN>
__global__ __launch_bounds__(256, 4)
void adder_conv(const float* __restrict__ x, const unsigned* __restrict__ wT,
                const float2* __restrict__ ab, unsigned* __restrict__ part,
                int Cin, int H, int W, int Wo, int Cout,
                int stride, int pad, int cpz, int P, int PI, int Pp)
{
    constexpr int KC = 32;
    __shared__ unsigned xs[KC][68];  // 64 pix, stride 68: conflict-light
    __shared__ unsigned ws[KC][128]; // 128 och
    __shared__ float2 abls[512];

    const int t  = threadIdx.x;
    const int tx = t & 15, ty = t >> 4;          // compute: 4 pix x 8 och
    const int ptile = blockIdx.x * 64, otile = blockIdx.y * 128;
    const int pp = t & 63, rg = t >> 6;          // xs staging: pixel, k-group
    const int oq = t & 31, kr = t >> 5;          // ws staging: och-quad, k-row

    if (BN) {
        for (int i = t; i < Cin; i += 256) abls[i] = ab[i];
        __syncthreads();
    }

    // staging pixel decode (fixed per thread)
    const int p_st = ptile + pp;
    const bool pv = p_st < P;
    int n_st = 0, q = 0;
    if (pv) { n_st = p_st / PI; q = p_st - n_st * PI; }
    const int oh = q / Wo, ow = q - oh * Wo;
    const int ih0 = oh * stride - pad, iw0 = ow * stride - pad;
    const int HWi = H * W;
    const float* xb = x + (size_t)n_st * Cin * HWi;
    const unsigned* wbase = wT + otile + oq * 4;

    unsigned acc[4][8] = {};

    const int chunkBeg = blockIdx.z * cpz, chunkEnd = chunkBeg + cpz;

    // ---- prefetch state: NAMED scalars only
    float xr0, xr1, xr2, xr3, xr4, xr5, xr6, xr7;
    uint4 wr0, wr1, wr2, wr3;
    int c0P = 0; bool vP = false;

#define ISSUE(CH) do {                                                        \
        const int k0_ = (CH) * KC;                                            \
        int c0_, ih_, iw_;                                                    \
        if (IS3x3) {                                                          \
            const int tap_ = k0_ / Cin;          /* uniform: Cin%32==0 */     \
            c0_ = k0_ - tap_ * Cin;                                           \
            const int kh_ = tap_ / 3, kw_ = tap_ - kh_ * 3;                   \
            ih_ = ih0 + kh_; iw_ = iw0 + kw_;                                 \
        } else { c0_ = k0_; ih_ = ih0; iw_ = iw0; }                           \
        vP = pv && (!IS3x3 || (ih_ >= 0 && ih_ < H && iw_ >= 0 && iw_ < W));  \
        c0P = c0_;                                                            \
        const float* px_ = xb + (size_t)(c0_ + rg) * HWi + (ih_ * W + iw_);   \
        xr0 = vP ? px_[0] : 0.f;                                              \
        xr1 = vP ? px_[(size_t) 4 * HWi] : 0.f;                               \
        xr2 = vP ? px_[(size_t) 8 * HWi] : 0.f;                               \
        xr3 = vP ? px_[(size_t)12 * HWi] : 0.f;                               \
        xr4 = vP ? px_[(size_t)16 * HWi] : 0.f;                               \
        xr5 = vP ? px_[(size_t)20 * HWi] : 0.f;                               \
        xr6 = vP ? px_[(size_t)24 * HWi] : 0.f;                               \
        xr7 = vP ? px_[(size_t)28 * HWi] : 0.f;                               \
        const unsigned* pw_ = wbase + (size_t)(k0_ + kr) * Cout;              \
        wr0 = *(const uint4*)(pw_);                                           \
        wr1 = *(const uint4*)(pw_ + (size_t) 8 * Cout);                       \
        wr2 = *(const uint4*)(pw_ + (size_t)16 * Cout);                       \
        wr3 = *(const uint4*)(pw_ + (size_t)24 * Cout);                       \
    } while (0)

    // BN (optional) then quantize: u = trunc(v*2^17 + 2^20 + 0.5)
#define BNQ(V, J, DST)                                                        \
        {                                                                     \
            float vv_ = V;                                                    \
            if (BN) {                                                         \
                const float2 s_ = abls[c0P + rg + 4 * (J)];                   \
                vv_ = fminf(fmaxf(fmaf(s_.x, vv_, s_.y), 0.f), 6.f);          \
                vv_ = vP ? vv_ : 0.f;      /* padding stays literal 0 */      \
            }                                                                 \
            DST = (unsigned)fmaf(vv_, QSCALE, QBIAS);                         \
        }

#define WRITE_LDS() do {                                                      \
        unsigned q0_, q1_, q2_, q3_, q4_, q5_, q6_, q7_;                      \
        BNQ(xr0, 0, q0_) BNQ(xr1, 1, q1_) BNQ(xr2, 2, q2_) BNQ(xr3, 3, q3_)   \
        BNQ(xr4, 4, q4_) BNQ(xr5, 5, q5_) BNQ(xr6, 6, q6_) BNQ(xr7, 7, q7_)   \
        xs[rg     ][pp] = q0_; xs[rg +  4][pp] = q1_;                         \
        xs[rg +  8][pp] = q2_; xs[rg + 12][pp] = q3_;                         \
        xs[rg + 16][pp] = q4_; xs[rg + 20][pp] = q5_;                         \
        xs[rg + 24][pp] = q6_; xs[rg + 28][pp] = q7_;                         \
        *(uint4*)&ws[kr     ][oq * 4] = wr0;                                  \
        *(uint4*)&ws[kr +  8][oq * 4] = wr1;                                  \
        *(uint4*)&ws[kr + 16][oq * 4] = wr2;                                  \
        *(uint4*)&ws[kr + 24][oq * 4] = wr3;                                  \
    } while (0)

    ISSUE(chunkBeg);

    for (int ch = chunkBeg; ch < chunkEnd; ++ch) {
        // [A] regs -> LDS (BN + quantize fused)
        WRITE_LDS();
        // [B] issue next chunk's global loads (vmcnt never drained in-loop)
        if (ch + 1 < chunkEnd) ISSUE(ch + 1);
        // [C] only the LDS writes must be visible before the barrier
        asm volatile("s_waitcnt lgkmcnt(0)" ::: "memory");
        __builtin_amdgcn_s_barrier();
        asm volatile("" ::: "memory");

        // ---- inner: 3 ds_read_b128 + 32 v_sad_u32 per kk
#pragma unroll 2
        for (int kk = 0; kk < KC; ++kk) {
            const uint4 xv = *(const uint4*)&xs[kk][tx * 4];
            const uint4 wa = *(const uint4*)&ws[kk][ty * 8];
            const uint4 wb = *(const uint4*)&ws[kk][ty * 8 + 4];
#define S1(A, XC, WC) asm("v_sad_u32 %0, %1, %2, %0" : "+v"(A) : "v"(XC), "v"(WC));
#define SROW(I, XC)                                             \
            S1(acc[I][0], XC, wa.x) S1(acc[I][1], XC, wa.y)     \
            S1(acc[I][2], XC, wa.z) S1(acc[I][3], XC, wa.w)     \
            S1(acc[I][4], XC, wb.x) S1(acc[I][5], XC, wb.y)     \
            S1(acc[I][6], XC, wb.z) S1(acc[I][7], XC, wb.w)
            SROW(0, xv.x) SROW(1, xv.y) SROW(2, xv.z) SROW(3, xv.w)
#undef SROW
#undef S1
        }
        asm volatile("" ::: "memory");
        __builtin_amdgcn_s_barrier();
        asm volatile("" ::: "memory");
    }
#undef ISSUE
#undef BNQ
#undef WRITE_LDS

    // ---- plain coalesced stores into this z-slice's partial buffer
    const int p0 = ptile + tx * 4;
    const bool full = (p0 + 3) < P;
#pragma unroll
    for (int jj = 0; jj < 8; ++jj) {
        const int o = otile + ty * 8 + jj;
        unsigned* dst = part + ((size_t)blockIdx.z * Cout + o) * Pp + p0;
        if (full) {
            *(uint4*)dst = make_uint4(acc[0][jj], acc[1][jj], acc[2][jj], acc[3][jj]);
        } else {
#pragma unroll
            for (int i = 0; i < 4; ++i)
                if (p0 + i < P) dst[i] = acc[i][jj];
        }
    }
}

// fused: sum Z u32 partial slices, rescale + negate -> float [n][c][PI], and
// accumulate per-channel sum/sumsq (double) for BN stats.
__global__ void combine_stats(const unsigned* __restrict__ part, float* __restrict__ fin,
                              double* __restrict__ st, int C, int PI, int Z, int Pp)
{
    const int c = blockIdx.x, n = blockIdx.y, t = threadIdx.x;
    const int pbase = n * PI;
    double s = 0.0, s2 = 0.0;
    for (int qq = t; qq < PI; qq += 256) {
        unsigned long long u = 0;
        for (int z = 0; z < Z; ++z)
            u += part[((size_t)z * C + c) * Pp + pbase + qq];
        const float v = -(float)((double)u * QINV);
        fin[((size_t)n * C + c) * PI + qq] = v;
        s += v; s2 += (double)v * v;
    }
    __shared__ double sh[256], sh2[256];
    sh[t] = s; sh2[t] = s2; __syncthreads();
    for (int off = 128; off > 0; off >>= 1) {
        if (t < off) { sh[t] += sh[t + off]; sh2[t] += sh2[t + off]; }
        __syncthreads();
    }
    if (t == 0) {
        unsafeAtomicAdd(&st[2 * c], sh[0]);
        unsafeAtomicAdd(&st[2 * c + 1], sh2[0]);
    }
}

// per-channel affine fold: a = g*rsqrt(var+eps), b = beta - mean*a
__global__ void ab_kernel(const double* __restrict__ st, const float* __restrict__ gamma,
                          const float* __restrict__ beta, float2* __restrict__ ab,
                          int C, double invCount)
{
    const int c = blockIdx.x * blockDim.x + threadIdx.x;
    if (c < C) {
        const double mean = st[2 * c] * invCount;
        const double var  = st[2 * c + 1] * invCount - mean * mean;
        const float a = gamma[c] * rsqrtf((float)var + 1e-5f);
        const float b = beta[c] - (float)mean * a;
        ab[c] = make_float2(a, b);
    }
}

// final BN+ReLU6 -> d_out
__global__ void apply_kernel(const float* __restrict__ y, const float2* __restrict__ ab,
                             float* __restrict__ out, int total, int C, int PI)
{
    const int i = blockIdx.x * 256 + threadIdx.x;
    if (i < total) {
        const int c = (i / PI) % C;
        const float2 s = ab[c];
        out[i] = fminf(fmaxf(fmaf(s.x, y[i], s.y), 0.f), 6.f);
    }
}

// merged weight transposes + fixed-point quantize:
// w [Cout][Cin][tap] -> wT [tap*Cin + c][Cout], u32 = round(w*2^17) + 2^20
struct TDesc { const float* w; unsigned* wT; int Cout; int Cin; int Tap; int elems; };
struct TPack { TDesc d[6]; };

__global__ void transpose_all(TPack p)
{
    const TDesc d = p.d[blockIdx.y];
    const int i = blockIdx.x * 256 + threadIdx.x;
    if (i < d.elems) {
        const int k = i / d.Cout, o = i - k * d.Cout;
        const int tap = k / d.Cin, c = k - tap * d.Cin;
        const float v = d.w[((size_t)o * d.Cin + c) * d.Tap + tap];
        d.wT[i] = (unsigned)fmaf(v, QSCALE, QBIAS);
    }
}

extern "C" void kernel_launch(void* const* d_in, const int* in_sizes, int n_in,
                              void* d_out, int out_size, void* d_ws, size_t ws_size,
                              hipStream_t stream)
{
    const float* x = (const float*)d_in[0];
    const float *w[6], *g[6], *bt[6];
    for (int i = 0; i < 6; ++i) {
        w[i]  = (const float*)d_in[1 + 3 * i];
        g[i]  = (const float*)d_in[2 + 3 * i];
        bt[i] = (const float*)d_in[3 + 3 * i];
    }

    char* ws = (char*)d_ws;
    float* bufA = (float*)ws;                                   // 23,658,496 B
    float* bufB = (float*)(ws + 23658496);                      // 11,829,248 B
    unsigned* part = (unsigned*)(ws + 23658496 + 11829248);     // 23,658,496 B
    size_t off = 23658496 + 11829248 + 23658496;
    const int wElems[6] = {256 * 512, 512 * 2304, 128 * 512,
                           256 * 1152, 128 * 256, 256 * 1152};
    unsigned* wT[6];
    for (int i = 0; i < 6; ++i) { wT[i] = (unsigned*)(ws + off); off += (size_t)wElems[i] * 4; }
    double* st = (double*)(ws + off); off += 3072 * 8;
    float2* ab = (float2*)(ws + off);
    const int stOff[6] = {0, 512, 1536, 1792, 2304, 2560};
    const int abOff[6] = {0, 256, 768, 896, 1152, 1280};

    const dim3 blk(256);

    // zero stats accumulators (ws is poisoned 0xAA before every launch)
    hipMemsetAsync(st, 0, 3072 * 8, stream);

    // merged weight transposes (tap-major k order) + quantize
    TPack tp;
    const int wCout[6] = {256, 512, 128, 256, 128, 256};
    const int wCin[6]  = {512, 256, 512, 128, 256, 128};
    const int wTap[6]  = {1, 9, 1, 9, 1, 9};
    for (int i = 0; i < 6; ++i)
        tp.d[i] = TDesc{w[i], wT[i], wCout[i], wCin[i], wTap[i], wElems[i]};
    transpose_all<<<dim3((1179648 + 255) / 256, 6), blk, 0, stream>>>(tp);

    // ---- L1: 1x1, 512->256, 38x38, P=23104, K=512, Z=1 (722 blocks)
    adder_conv<false, false><<<dim3(361, 2, 1), blk, 0, stream>>>(
        x, wT[0], nullptr, part, 512, 38, 38, 38, 256, 1, 0, 16, 23104, 1444, 23104);
    combine_stats<<<dim3(256, 16), blk, 0, stream>>>(part, bufA, st + stOff[0], 256, 1444, 1, 23104);
    ab_kernel<<<1, blk, 0, stream>>>(st + stOff[0], g[0], bt[0], ab + abOff[0], 256, 1.0 / 23104);

    // ---- L2: 3x3 s2 p1, 256->512, 38->19, P=5776, K=2304, Z=2 (728 blocks)
    adder_conv<true, true><<<dim3(91, 4, 2), blk, 0, stream>>>(
        bufA, wT[1], ab + abOff[0], part, 256, 38, 38, 19, 512, 2, 1, 36, 5776, 361, 5776);
    combine_stats<<<dim3(512, 16), blk, 0, stream>>>(part, bufB, st + stOff[1], 512, 361, 2, 5776);
    ab_kernel<<<2, blk, 0, stream>>>(st + stOff[1], g[1], bt[1], ab + abOff[1], 512, 1.0 / 5776);

    // ---- L3: 1x1, 512->128, 19x19, P=5776, K=512, Z=8 (728 blocks)
    adder_conv<false, true><<<dim3(91, 1, 8), blk, 0, stream>>>(
        bufB, wT[2], ab + abOff[1], part, 512, 19, 19, 19, 128, 1, 0, 2, 5776, 361, 5776);
    combine_stats<<<dim3(128, 16), blk, 0, stream>>>(part, bufA, st + stOff[2], 128, 361, 8, 5776);
    ab_kernel<<<1, blk, 0, stream>>>(st + stOff[2], g[2], bt[2], ab + abOff[2], 128, 1.0 / 5776);

    // ---- L4: 3x3 s2 p1, 128->256, 19->10, P=1600, K=1152, Z=12 (600 blocks)
    adder_conv<true, true><<<dim3(25, 2, 12), blk, 0, stream>>>(
        bufA, wT[3], ab + abOff[2], part, 128, 19, 19, 10, 256, 2, 1, 3, 1600, 100, 1600);
    combine_stats<<<dim3(256, 16), blk, 0, stream>>>(part, bufB, st + stOff[3], 256, 100, 12, 1600);
    ab_kernel<<<1, blk, 0, stream>>>(st + stOff[3], g[3], bt[3], ab + abOff[3], 256, 1.0 / 1600);

    // ---- L5: 1x1, 256->128, 10x10, P=1600, K=256, Z=8 (200 blocks)
    adder_conv<false, true><<<dim3(25, 1, 8), blk, 0, stream>>>(
        bufB, wT[4], ab + abOff[3], part, 256, 10, 10, 10, 128, 1, 0, 1, 1600, 100, 1600);
    combine_stats<<<dim3(128, 16), blk, 0, stream>>>(part, bufA, st + stOff[4], 128, 100, 8, 1600);
    ab_kernel<<<1, blk, 0, stream>>>(st + stOff[4], g[4], bt[4], ab + abOff[4], 128, 1.0 / 1600);

    // ---- L6: 3x3 s2 p0, 128->256, 10->4, P=256, K=1152, Z=18 (144 blocks)
    adder_conv<true, true><<<dim3(4, 2, 18), blk, 0, stream>>>(
        bufA, wT[5], ab + abOff[4], part, 128, 10, 10, 4, 256, 2, 0, 2, 256, 16, 256);
    combine_stats<<<dim3(256, 16), blk, 0, stream>>>(part, bufB, st + stOff[5], 256, 16, 18, 256);
    ab_kernel<<<1, blk, 0, stream>>>(st + stOff[5], g[5], bt[5], ab + abOff[5], 256, 1.0 / 256);

    // ---- final BN+ReLU6 -> out
    apply_kernel<<<(65536 + 255) / 256, blk, 0, stream>>>(bufB, ab + abOff[5], (float*)d_out,
                                                          65536, 256, 16);
}